// Round 1
// baseline (10140.167 us; speedup 1.0000x reference)
//
#include <hip/hip_runtime.h>

#define NUM_USERS 100000
#define NUM_ITEMS 50000
#define N_TOTAL   150000
#define LATENT    64
#define BATCH     16384

// ---- init u_acc / i_acc from the raw embeddings (layer-0 contribution) ----
__global__ void init_acc_kernel(const float* __restrict__ user_emb,
                                const float* __restrict__ item_emb,
                                const int* __restrict__ users,
                                const int* __restrict__ items,
                                float* __restrict__ u_acc,
                                float* __restrict__ i_acc) {
    int tid = blockIdx.x * blockDim.x + threadIdx.x;
    int b = tid >> 6, d = tid & 63;
    if (b >= BATCH) return;
    u_acc[tid] = user_emb[(long long)users[b] * LATENT + d];
    i_acc[tid] = item_emb[(long long)items[b] * LATENT + d];
}

// ---- COO SpMM: y[row] += val * x[col], 16 threads/edge, float4 per thread ----
__global__ void spmm_atomic_kernel(const float* __restrict__ vals,
                                   const int* __restrict__ rows,
                                   const int* __restrict__ cols,
                                   const float* __restrict__ x,
                                   float* __restrict__ y, int nnz) {
    long long tid = (long long)blockIdx.x * blockDim.x + threadIdx.x;
    int e = (int)(tid >> 4);
    if (e >= nnz) return;
    int d = ((int)tid & 15) << 2;
    float v = vals[e];
    int c = cols[e];
    int r = rows[e];
    const float4 xv = *reinterpret_cast<const float4*>(x + (long long)c * LATENT + d);
    float* yp = y + (long long)r * LATENT + d;
    atomicAdd(yp + 0, v * xv.x);
    atomicAdd(yp + 1, v * xv.y);
    atomicAdd(yp + 2, v * xv.z);
    atomicAdd(yp + 3, v * xv.w);
}

// ---- accumulate the gathered rows of the freshly computed layer ----
__global__ void gather_acc_kernel(const float* __restrict__ emb,
                                  const int* __restrict__ users,
                                  const int* __restrict__ items,
                                  float* __restrict__ u_acc,
                                  float* __restrict__ i_acc) {
    int tid = blockIdx.x * blockDim.x + threadIdx.x;
    int b = tid >> 6, d = tid & 63;
    if (b >= BATCH) return;
    u_acc[tid] += emb[(long long)users[b] * LATENT + d];
    i_acc[tid] += emb[((long long)items[b] + NUM_USERS) * LATENT + d];
}

// ---- final: gamma[b] = dot(u_acc[b], i_acc[b]) / 16  (acc/4 on both sides) ----
__global__ void dot_kernel(const float* __restrict__ u_acc,
                           const float* __restrict__ i_acc,
                           float* __restrict__ out) {
    int b = blockIdx.x;
    int d = threadIdx.x;  // 64 lanes = 1 wave
    float p = u_acc[b * 64 + d] * i_acc[b * 64 + d];
    #pragma unroll
    for (int off = 32; off; off >>= 1) p += __shfl_down(p, off, 64);
    if (d == 0) out[b] = p * (1.0f / 16.0f);
}

extern "C" void kernel_launch(void* const* d_in, const int* in_sizes, int n_in,
                              void* d_out, int out_size, void* d_ws, size_t ws_size,
                              hipStream_t stream) {
    const float* user_emb = (const float*)d_in[0];
    const float* item_emb = (const float*)d_in[1];
    const float* vals     = (const float*)d_in[2];
    const int*   rows     = (const int*)d_in[3];
    const int*   cols     = (const int*)d_in[4];
    const int*   users    = (const int*)d_in[5];
    const int*   items    = (const int*)d_in[6];
    float* out = (float*)d_out;

    const int nnz = in_sizes[2];

    char* ws = (char*)d_ws;
    const size_t embBytes = (size_t)N_TOTAL * LATENT * sizeof(float);   // 38.4 MB
    const size_t accBytes = (size_t)BATCH * LATENT * sizeof(float);     // 4 MB
    float* emb_a = (float*)ws;
    float* emb_b = (float*)(ws + embBytes);
    float* u_acc = (float*)(ws + 2 * embBytes);
    float* i_acc = (float*)(ws + 2 * embBytes + accBytes);

    // emb_a = concat(user_emb, item_emb)
    hipMemcpyAsync(emb_a, user_emb, (size_t)NUM_USERS * LATENT * sizeof(float),
                   hipMemcpyDeviceToDevice, stream);
    hipMemcpyAsync(emb_a + (size_t)NUM_USERS * LATENT, item_emb,
                   (size_t)NUM_ITEMS * LATENT * sizeof(float),
                   hipMemcpyDeviceToDevice, stream);

    init_acc_kernel<<<(BATCH * 64) / 256, 256, 0, stream>>>(
        user_emb, item_emb, users, items, u_acc, i_acc);

    float* cur = emb_a;
    float* nxt = emb_b;
    for (int l = 0; l < 3; ++l) {
        hipMemsetAsync(nxt, 0, embBytes, stream);
        long long threads = (long long)nnz * 16;
        int blocks = (int)((threads + 255) / 256);
        spmm_atomic_kernel<<<blocks, 256, 0, stream>>>(vals, rows, cols, cur, nxt, nnz);
        gather_acc_kernel<<<(BATCH * 64) / 256, 256, 0, stream>>>(
            nxt, users, items, u_acc, i_acc);
        float* t = cur; cur = nxt; nxt = t;
    }

    dot_kernel<<<BATCH, 64, 0, stream>>>(u_acc, i_acc, out);
}

// Round 2
// 1201.737 us; speedup vs baseline: 8.4379x; 8.4379x over previous
//
#include <hip/hip_runtime.h>

#define NUM_USERS 100000
#define NUM_ITEMS 50000
#define N_TOTAL   150000
#define LATENT    64
#define BATCH     16384
#define SCAN_T    1024

// ---- 1. histogram of row indices ----
__global__ void hist_kernel(const int* __restrict__ rows, int* __restrict__ cnt, int nnz) {
    int stride = gridDim.x * blockDim.x;
    for (int e = blockIdx.x * blockDim.x + threadIdx.x; e < nnz; e += stride)
        atomicAdd(&cnt[rows[e]], 1);
}

// ---- 2. single-block exclusive scan over 150001 entries ----
__global__ void scan_kernel(const int* __restrict__ cnt, int* __restrict__ rowptr) {
    __shared__ int partial[SCAN_T];
    int t = threadIdx.x;
    const int chunk = (N_TOTAL + SCAN_T - 1) / SCAN_T;
    int lo = t * chunk;
    int hi = lo + chunk; if (hi > N_TOTAL) hi = N_TOTAL;
    if (lo > N_TOTAL) lo = N_TOTAL;
    int s = 0;
    for (int i = lo; i < hi; ++i) s += cnt[i];
    partial[t] = s;
    __syncthreads();
    // Hillis-Steele inclusive scan in LDS
    for (int d = 1; d < SCAN_T; d <<= 1) {
        int v = (t >= d) ? partial[t - d] : 0;
        __syncthreads();
        partial[t] += v;
        __syncthreads();
    }
    int off = partial[t] - s;  // exclusive prefix for this thread's chunk
    for (int i = lo; i < hi; ++i) { rowptr[i] = off; off += cnt[i]; }
    if (t == SCAN_T - 1) rowptr[N_TOTAL] = off;
}

// ---- 3. cursor = rowptr copy ----
__global__ void copy_cursor_kernel(const int* __restrict__ rowptr, int* __restrict__ cursor) {
    int i = blockIdx.x * blockDim.x + threadIdx.x;
    if (i < N_TOTAL) cursor[i] = rowptr[i];
}

// ---- 4. scatter edges into CSR order ----
__global__ void scatter_kernel(const int* __restrict__ rows, const int* __restrict__ cols,
                               const float* __restrict__ vals,
                               int* __restrict__ cursor,
                               int* __restrict__ ecol, float* __restrict__ eval, int nnz) {
    int stride = gridDim.x * blockDim.x;
    for (int e = blockIdx.x * blockDim.x + threadIdx.x; e < nnz; e += stride) {
        int r = rows[e];
        int pos = atomicAdd(&cursor[r], 1);
        ecol[pos] = cols[e];
        eval[pos] = vals[e];
    }
}

// ---- 5. CSR SpMM: one wave per row, lane d owns dim d ----
__global__ void spmm_csr_kernel(const int* __restrict__ rowptr,
                                const int* __restrict__ ecol,
                                const float* __restrict__ eval,
                                const float* __restrict__ x,
                                float* __restrict__ y) {
    int row = blockIdx.x * 4 + (threadIdx.x >> 6);
    int d = threadIdx.x & 63;
    int s = rowptr[row], e = rowptr[row + 1];
    float acc = 0.f;
    int i = s;
    for (; i + 4 <= e; i += 4) {
        int   c0 = ecol[i],  c1 = ecol[i + 1],  c2 = ecol[i + 2],  c3 = ecol[i + 3];
        float v0 = eval[i],  v1 = eval[i + 1],  v2 = eval[i + 2],  v3 = eval[i + 3];
        float x0 = x[(size_t)c0 * LATENT + d];
        float x1 = x[(size_t)c1 * LATENT + d];
        float x2 = x[(size_t)c2 * LATENT + d];
        float x3 = x[(size_t)c3 * LATENT + d];
        acc = fmaf(v0, x0, acc);
        acc = fmaf(v1, x1, acc);
        acc = fmaf(v2, x2, acc);
        acc = fmaf(v3, x3, acc);
    }
    for (; i < e; ++i) acc = fmaf(eval[i], x[(size_t)ecol[i] * LATENT + d], acc);
    y[(size_t)row * LATENT + d] = acc;
}

// ---- init u_acc / i_acc from the raw embeddings (layer-0 contribution) ----
__global__ void init_acc_kernel(const float* __restrict__ user_emb,
                                const float* __restrict__ item_emb,
                                const int* __restrict__ users,
                                const int* __restrict__ items,
                                float* __restrict__ u_acc,
                                float* __restrict__ i_acc) {
    int tid = blockIdx.x * blockDim.x + threadIdx.x;
    int b = tid >> 6, d = tid & 63;
    if (b >= BATCH) return;
    u_acc[tid] = user_emb[(size_t)users[b] * LATENT + d];
    i_acc[tid] = item_emb[(size_t)items[b] * LATENT + d];
}

// ---- accumulate gathered rows of the fresh layer ----
__global__ void gather_acc_kernel(const float* __restrict__ emb,
                                  const int* __restrict__ users,
                                  const int* __restrict__ items,
                                  float* __restrict__ u_acc,
                                  float* __restrict__ i_acc) {
    int tid = blockIdx.x * blockDim.x + threadIdx.x;
    int b = tid >> 6, d = tid & 63;
    if (b >= BATCH) return;
    u_acc[tid] += emb[(size_t)users[b] * LATENT + d];
    i_acc[tid] += emb[((size_t)items[b] + NUM_USERS) * LATENT + d];
}

// ---- gamma[b] = dot(u_acc[b], i_acc[b]) / 16 ----
__global__ void dot_kernel(const float* __restrict__ u_acc,
                           const float* __restrict__ i_acc,
                           float* __restrict__ out) {
    int b = blockIdx.x;
    int d = threadIdx.x;  // 64 lanes = 1 wave
    float p = u_acc[b * 64 + d] * i_acc[b * 64 + d];
    #pragma unroll
    for (int off = 32; off; off >>= 1) p += __shfl_down(p, off, 64);
    if (d == 0) out[b] = p * (1.0f / 16.0f);
}

extern "C" void kernel_launch(void* const* d_in, const int* in_sizes, int n_in,
                              void* d_out, int out_size, void* d_ws, size_t ws_size,
                              hipStream_t stream) {
    const float* user_emb = (const float*)d_in[0];
    const float* item_emb = (const float*)d_in[1];
    const float* vals     = (const float*)d_in[2];
    const int*   rows     = (const int*)d_in[3];
    const int*   cols     = (const int*)d_in[4];
    const int*   users    = (const int*)d_in[5];
    const int*   items    = (const int*)d_in[6];
    float* out = (float*)d_out;

    const int nnz = in_sizes[2];

    char* ws = (char*)d_ws;
    const size_t embBytes = (size_t)N_TOTAL * LATENT * sizeof(float);   // 38.4 MB
    const size_t accBytes = (size_t)BATCH * LATENT * sizeof(float);     // 4 MB
    const size_t edgeIB   = (size_t)nnz * sizeof(int);                  // 16 MB
    const size_t edgeFB   = (size_t)nnz * sizeof(float);                // 16 MB

    size_t off = 0;
    float* emb_a  = (float*)(ws + off); off += embBytes;
    float* emb_b  = (float*)(ws + off); off += embBytes;
    float* u_acc  = (float*)(ws + off); off += accBytes;
    float* i_acc  = (float*)(ws + off); off += accBytes;
    int*   ecol   = (int*)  (ws + off); off += edgeIB;
    float* eval_  = (float*)(ws + off); off += edgeFB;
    int*   rowptr = (int*)  (ws + off); off += (size_t)(N_TOTAL + 1) * sizeof(int);
    int*   cursor = (int*)  (ws + off); off += (size_t)N_TOTAL * sizeof(int);

    // emb_a = concat(user_emb, item_emb)
    hipMemcpyAsync(emb_a, user_emb, (size_t)NUM_USERS * LATENT * sizeof(float),
                   hipMemcpyDeviceToDevice, stream);
    hipMemcpyAsync(emb_a + (size_t)NUM_USERS * LATENT, item_emb,
                   (size_t)NUM_ITEMS * LATENT * sizeof(float),
                   hipMemcpyDeviceToDevice, stream);

    // --- CSR build (cursor doubles as the histogram buffer) ---
    hipMemsetAsync(cursor, 0, (size_t)N_TOTAL * sizeof(int), stream);
    int eblocks = (nnz + 255) / 256; if (eblocks > 4096) eblocks = 4096;
    hist_kernel<<<eblocks, 256, 0, stream>>>(rows, cursor, nnz);
    scan_kernel<<<1, SCAN_T, 0, stream>>>(cursor, rowptr);
    copy_cursor_kernel<<<(N_TOTAL + 255) / 256, 256, 0, stream>>>(rowptr, cursor);
    scatter_kernel<<<eblocks, 256, 0, stream>>>(rows, cols, vals, cursor, ecol, eval_, nnz);

    init_acc_kernel<<<(BATCH * 64) / 256, 256, 0, stream>>>(
        user_emb, item_emb, users, items, u_acc, i_acc);

    float* cur = emb_a;
    float* nxt = emb_b;
    for (int l = 0; l < 3; ++l) {
        spmm_csr_kernel<<<N_TOTAL / 4, 256, 0, stream>>>(rowptr, ecol, eval_, cur, nxt);
        gather_acc_kernel<<<(BATCH * 64) / 256, 256, 0, stream>>>(
            nxt, users, items, u_acc, i_acc);
        float* t = cur; cur = nxt; nxt = t;
    }

    dot_kernel<<<BATCH, 64, 0, stream>>>(u_acc, i_acc, out);
}

// Round 3
// 563.393 us; speedup vs baseline: 17.9984x; 2.1330x over previous
//
#include <hip/hip_runtime.h>

#define NUM_USERS 100000
#define NUM_ITEMS 50000
#define N_TOTAL   150000
#define LATENT    64
#define BATCH     16384
#define BROWS     512                 // rows per coarse bucket
#define NB        293                 // ceil(N_TOTAL / BROWS)

typedef unsigned int u32;
typedef unsigned short u16;

__device__ __forceinline__ u16 f32_to_bf16(float f) {
    u32 u = __float_as_uint(f);
    u32 r = (u + 0x7FFFu + ((u >> 16) & 1u)) >> 16;   // round-to-nearest-even
    return (u16)r;
}
__device__ __forceinline__ float bf16_to_f32(u16 b) {
    return __uint_as_float(((u32)b) << 16);
}

// ---- coarse histogram: bucket = row >> 9 ----
__global__ void coarse_hist_kernel(const int* __restrict__ rows, int* __restrict__ ccnt, int nnz) {
    __shared__ int h[NB];
    for (int i = threadIdx.x; i < NB; i += blockDim.x) h[i] = 0;
    __syncthreads();
    int stride = gridDim.x * blockDim.x;
    for (int e = blockIdx.x * blockDim.x + threadIdx.x; e < nnz; e += stride)
        atomicAdd(&h[rows[e] >> 9], 1);
    __syncthreads();
    for (int i = threadIdx.x; i < NB; i += blockDim.x)
        if (h[i]) atomicAdd(&ccnt[i], h[i]);
}

// ---- scan 293 bucket counts -> coarse ptr + cursor; also rowptr[N_TOTAL] ----
__global__ void coarse_scan_kernel(const int* __restrict__ ccnt, int* __restrict__ cptr,
                                   int* __restrict__ ccur, int* __restrict__ rowptr, int nnz) {
    __shared__ int s[512];
    int t = threadIdx.x;
    int v = (t < NB) ? ccnt[t] : 0;
    s[t] = v;
    __syncthreads();
    for (int d = 1; d < 512; d <<= 1) {
        int x = (t >= d) ? s[t - d] : 0;
        __syncthreads();
        s[t] += x;
        __syncthreads();
    }
    int excl = s[t] - v;
    if (t < NB) { cptr[t] = excl; ccur[t] = excl; }
    if (t == 0) { cptr[NB] = nnz; rowptr[N_TOTAL] = nnz; }
}

// ---- pass 1: partition edges into coarse buckets (block-local run => line-local writes) ----
__global__ void partition1_kernel(const int* __restrict__ rows, const int* __restrict__ cols,
                                  const float* __restrict__ vals,
                                  int* __restrict__ ccur, uint2* __restrict__ packed0, int nnz) {
    __shared__ int lh[NB];
    __shared__ int lc[NB];
    int t = threadIdx.x;
    for (int i = t; i < NB; i += blockDim.x) lh[i] = 0;
    __syncthreads();
    int epb = (nnz + gridDim.x - 1) / gridDim.x;
    int s0 = blockIdx.x * epb;
    int s1 = s0 + epb; if (s1 > nnz) s1 = nnz;
    for (int e = s0 + t; e < s1; e += blockDim.x)
        atomicAdd(&lh[rows[e] >> 9], 1);
    __syncthreads();
    for (int i = t; i < NB; i += blockDim.x) {
        int c = lh[i];
        lc[i] = c ? atomicAdd(&ccur[i], c) : 0;
    }
    __syncthreads();
    for (int e = s0 + t; e < s1; e += blockDim.x) {
        int r = rows[e];
        int pos = atomicAdd(&lc[r >> 9], 1);
        packed0[pos] = make_uint2((u32)cols[e] | ((u32)(r & (BROWS - 1)) << 18),
                                  __float_as_uint(vals[e]));
    }
}

// ---- pass 2: per-bucket counting sort in LDS; emits rowptr + final edge list ----
__global__ void __launch_bounds__(BROWS)
partition2_kernel(const int* __restrict__ cptr, const uint2* __restrict__ packed0,
                  uint2* __restrict__ edges, int* __restrict__ rowptr) {
    __shared__ int cnt[BROWS];
    __shared__ int s[BROWS];
    __shared__ int cur[BROWS];
    int b = blockIdx.x;
    int t = threadIdx.x;
    int seg0 = cptr[b], seg1 = cptr[b + 1];
    cnt[t] = 0;
    __syncthreads();
    for (int i = seg0 + t; i < seg1; i += BROWS)
        atomicAdd(&cnt[packed0[i].x >> 18], 1);
    __syncthreads();
    int v = cnt[t];
    s[t] = v;
    __syncthreads();
    for (int d = 1; d < BROWS; d <<= 1) {
        int x = (t >= d) ? s[t - d] : 0;
        __syncthreads();
        s[t] += x;
        __syncthreads();
    }
    int excl = s[t] - v;
    cur[t] = excl;
    int r = (b << 9) + t;
    if (r < N_TOTAL) rowptr[r] = seg0 + excl;
    __syncthreads();
    for (int i = seg0 + t; i < seg1; i += BROWS) {
        uint2 p = packed0[i];
        int pos = seg0 + atomicAdd(&cur[p.x >> 18], 1);
        edges[pos] = make_uint2(p.x & 0x3FFFFu, p.y);
    }
}

// ---- convert original embeddings to bf16 layer-0 buffer ----
__global__ void convert_kernel(const float* __restrict__ ue, const float* __restrict__ ie,
                               u16* __restrict__ x) {
    int i = blockIdx.x * blockDim.x + threadIdx.x;
    if (i >= N_TOTAL * LATENT) return;
    float f = (i < NUM_USERS * LATENT) ? ue[i] : ie[i - NUM_USERS * LATENT];
    x[i] = f32_to_bf16(f);
}

// ---- CSR SpMM, bf16 x -> bf16 y, one wave per row, lane = dim ----
__global__ void spmm_kernel(const int* __restrict__ rowptr, const uint2* __restrict__ edges,
                            const u16* __restrict__ x, u16* __restrict__ y) {
    int row = blockIdx.x * 4 + (threadIdx.x >> 6);
    int d = threadIdx.x & 63;
    int s = rowptr[row], e = rowptr[row + 1];
    float acc = 0.f;
    int i = s;
    for (; i + 4 <= e; i += 4) {
        uint2 e0 = edges[i], e1 = edges[i + 1], e2 = edges[i + 2], e3 = edges[i + 3];
        float x0 = bf16_to_f32(x[(size_t)e0.x * LATENT + d]);
        float x1 = bf16_to_f32(x[(size_t)e1.x * LATENT + d]);
        float x2 = bf16_to_f32(x[(size_t)e2.x * LATENT + d]);
        float x3 = bf16_to_f32(x[(size_t)e3.x * LATENT + d]);
        acc = fmaf(__uint_as_float(e0.y), x0, acc);
        acc = fmaf(__uint_as_float(e1.y), x1, acc);
        acc = fmaf(__uint_as_float(e2.y), x2, acc);
        acc = fmaf(__uint_as_float(e3.y), x3, acc);
    }
    for (; i < e; ++i)
        acc = fmaf(__uint_as_float(edges[i].y), bf16_to_f32(x[(size_t)edges[i].x * LATENT + d]), acc);
    y[(size_t)row * LATENT + d] = f32_to_bf16(acc);
}

// ---- init u_acc / i_acc from the raw f32 embeddings (layer-0 contribution) ----
__global__ void init_acc_kernel(const float* __restrict__ user_emb,
                                const float* __restrict__ item_emb,
                                const int* __restrict__ users,
                                const int* __restrict__ items,
                                float* __restrict__ u_acc,
                                float* __restrict__ i_acc) {
    int tid = blockIdx.x * blockDim.x + threadIdx.x;
    int b = tid >> 6, d = tid & 63;
    if (b >= BATCH) return;
    u_acc[tid] = user_emb[(size_t)users[b] * LATENT + d];
    i_acc[tid] = item_emb[(size_t)items[b] * LATENT + d];
}

// ---- accumulate gathered bf16 rows of the fresh layer ----
__global__ void gather_acc_kernel(const u16* __restrict__ emb,
                                  const int* __restrict__ users,
                                  const int* __restrict__ items,
                                  float* __restrict__ u_acc,
                                  float* __restrict__ i_acc) {
    int tid = blockIdx.x * blockDim.x + threadIdx.x;
    int b = tid >> 6, d = tid & 63;
    if (b >= BATCH) return;
    u_acc[tid] += bf16_to_f32(emb[(size_t)users[b] * LATENT + d]);
    i_acc[tid] += bf16_to_f32(emb[((size_t)items[b] + NUM_USERS) * LATENT + d]);
}

// ---- gamma[b] = dot(u_acc[b], i_acc[b]) / 16 ----
__global__ void dot_kernel(const float* __restrict__ u_acc,
                           const float* __restrict__ i_acc,
                           float* __restrict__ out) {
    int b = blockIdx.x;
    int d = threadIdx.x;  // 64 lanes = 1 wave
    float p = u_acc[b * 64 + d] * i_acc[b * 64 + d];
    #pragma unroll
    for (int off = 32; off; off >>= 1) p += __shfl_down(p, off, 64);
    if (d == 0) out[b] = p * (1.0f / 16.0f);
}

extern "C" void kernel_launch(void* const* d_in, const int* in_sizes, int n_in,
                              void* d_out, int out_size, void* d_ws, size_t ws_size,
                              hipStream_t stream) {
    const float* user_emb = (const float*)d_in[0];
    const float* item_emb = (const float*)d_in[1];
    const float* vals     = (const float*)d_in[2];
    const int*   rows     = (const int*)d_in[3];
    const int*   cols     = (const int*)d_in[4];
    const int*   users    = (const int*)d_in[5];
    const int*   items    = (const int*)d_in[6];
    float* out = (float*)d_out;

    const int nnz = in_sizes[2];

    char* ws = (char*)d_ws;
    const size_t embB  = (size_t)N_TOTAL * LATENT * sizeof(u16);     // 19.2 MB
    const size_t accB  = (size_t)BATCH * LATENT * sizeof(float);     // 4 MB
    const size_t edgeB = (size_t)nnz * sizeof(uint2);                // 32 MB

    size_t off = 0;
    u16*   emb_a   = (u16*)  (ws + off); off += embB;
    u16*   emb_b   = (u16*)  (ws + off); off += embB;
    uint2* packed0 = (uint2*)(ws + off); off += edgeB;
    uint2* edges   = (uint2*)(ws + off); off += edgeB;
    float* u_acc   = (float*)(ws + off); off += accB;
    float* i_acc   = (float*)(ws + off); off += accB;
    int*   rowptr  = (int*)  (ws + off); off += (size_t)(N_TOTAL + 1) * sizeof(int);
    int*   ccnt    = (int*)  (ws + off); off += (size_t)(NB + 1) * sizeof(int);
    int*   cptr    = (int*)  (ws + off); off += (size_t)(NB + 1) * sizeof(int);
    int*   ccur    = (int*)  (ws + off); off += (size_t)(NB + 1) * sizeof(int);

    // --- CSR build: coarse hist -> scan -> 2-level partition ---
    hipMemsetAsync(ccnt, 0, (size_t)(NB + 1) * sizeof(int), stream);
    coarse_hist_kernel<<<512, 256, 0, stream>>>(rows, ccnt, nnz);
    coarse_scan_kernel<<<1, 512, 0, stream>>>(ccnt, cptr, ccur, rowptr, nnz);
    partition1_kernel<<<512, 256, 0, stream>>>(rows, cols, vals, ccur, packed0, nnz);
    partition2_kernel<<<NB, BROWS, 0, stream>>>(cptr, packed0, edges, rowptr);

    convert_kernel<<<(N_TOTAL * LATENT + 255) / 256, 256, 0, stream>>>(user_emb, item_emb, emb_a);
    init_acc_kernel<<<(BATCH * 64) / 256, 256, 0, stream>>>(
        user_emb, item_emb, users, items, u_acc, i_acc);

    u16* cur = emb_a;
    u16* nxt = emb_b;
    for (int l = 0; l < 3; ++l) {
        spmm_kernel<<<N_TOTAL / 4, 256, 0, stream>>>(rowptr, edges, cur, nxt);
        gather_acc_kernel<<<(BATCH * 64) / 256, 256, 0, stream>>>(
            nxt, users, items, u_acc, i_acc);
        u16* t = cur; cur = nxt; nxt = t;
    }

    dot_kernel<<<BATCH, 64, 0, stream>>>(u_acc, i_acc, out);
}

// Round 4
// 373.525 us; speedup vs baseline: 27.1472x; 1.5083x over previous
//
#include <hip/hip_runtime.h>

#define NUM_USERS 100000
#define NUM_ITEMS 50000
#define N_TOTAL   150000
#define LATENT    64
#define BATCH     16384
#define BROWS     512                 // rows per coarse bucket
#define NB        293                 // ceil(N_TOTAL / BROWS)

typedef unsigned int u32;
typedef unsigned short u16;

__device__ __forceinline__ u16 f32_to_bf16(float f) {
    u32 u = __float_as_uint(f);
    u32 r = (u + 0x7FFFu + ((u >> 16) & 1u)) >> 16;   // round-to-nearest-even
    return (u16)r;
}
__device__ __forceinline__ float bf16_lo(u32 w) { return __uint_as_float(w << 16); }
__device__ __forceinline__ float bf16_hi(u32 w) { return __uint_as_float(w & 0xFFFF0000u); }

// ---- coarse histogram: bucket = row >> 9 ----
__global__ void coarse_hist_kernel(const int* __restrict__ rows, int* __restrict__ ccnt, int nnz) {
    __shared__ int h[NB];
    for (int i = threadIdx.x; i < NB; i += blockDim.x) h[i] = 0;
    __syncthreads();
    int stride = gridDim.x * blockDim.x;
    for (int e = blockIdx.x * blockDim.x + threadIdx.x; e < nnz; e += stride)
        atomicAdd(&h[rows[e] >> 9], 1);
    __syncthreads();
    for (int i = threadIdx.x; i < NB; i += blockDim.x)
        if (h[i]) atomicAdd(&ccnt[i], h[i]);
}

// ---- scan 293 bucket counts -> coarse ptr + cursor; also rowptr[N_TOTAL] ----
__global__ void coarse_scan_kernel(const int* __restrict__ ccnt, int* __restrict__ cptr,
                                   int* __restrict__ ccur, int* __restrict__ rowptr, int nnz) {
    __shared__ int s[512];
    int t = threadIdx.x;
    int v = (t < NB) ? ccnt[t] : 0;
    s[t] = v;
    __syncthreads();
    for (int d = 1; d < 512; d <<= 1) {
        int x = (t >= d) ? s[t - d] : 0;
        __syncthreads();
        s[t] += x;
        __syncthreads();
    }
    int excl = s[t] - v;
    if (t < NB) { cptr[t] = excl; ccur[t] = excl; }
    if (t == 0) { cptr[NB] = nnz; rowptr[N_TOTAL] = nnz; }
}

// ---- pass 1: partition edges into coarse buckets ----
__global__ void partition1_kernel(const int* __restrict__ rows, const int* __restrict__ cols,
                                  const float* __restrict__ vals,
                                  int* __restrict__ ccur, uint2* __restrict__ packed0, int nnz) {
    __shared__ int lh[NB];
    __shared__ int lc[NB];
    int t = threadIdx.x;
    for (int i = t; i < NB; i += blockDim.x) lh[i] = 0;
    __syncthreads();
    int epb = (nnz + gridDim.x - 1) / gridDim.x;
    int s0 = blockIdx.x * epb;
    int s1 = s0 + epb; if (s1 > nnz) s1 = nnz;
    for (int e = s0 + t; e < s1; e += blockDim.x)
        atomicAdd(&lh[rows[e] >> 9], 1);
    __syncthreads();
    for (int i = t; i < NB; i += blockDim.x) {
        int c = lh[i];
        lc[i] = c ? atomicAdd(&ccur[i], c) : 0;
    }
    __syncthreads();
    for (int e = s0 + t; e < s1; e += blockDim.x) {
        int r = rows[e];
        int pos = atomicAdd(&lc[r >> 9], 1);
        packed0[pos] = make_uint2((u32)cols[e] | ((u32)(r & (BROWS - 1)) << 18),
                                  __float_as_uint(vals[e]));
    }
}

// ---- pass 2: per-bucket counting sort in LDS; emits rowptr + final edge list ----
__global__ void __launch_bounds__(BROWS)
partition2_kernel(const int* __restrict__ cptr, const uint2* __restrict__ packed0,
                  uint2* __restrict__ edges, int* __restrict__ rowptr) {
    __shared__ int cnt[BROWS];
    __shared__ int s[BROWS];
    __shared__ int cur[BROWS];
    int b = blockIdx.x;
    int t = threadIdx.x;
    int seg0 = cptr[b], seg1 = cptr[b + 1];
    cnt[t] = 0;
    __syncthreads();
    for (int i = seg0 + t; i < seg1; i += BROWS)
        atomicAdd(&cnt[packed0[i].x >> 18], 1);
    __syncthreads();
    int v = cnt[t];
    s[t] = v;
    __syncthreads();
    for (int d = 1; d < BROWS; d <<= 1) {
        int x = (t >= d) ? s[t - d] : 0;
        __syncthreads();
        s[t] += x;
        __syncthreads();
    }
    int excl = s[t] - v;
    cur[t] = excl;
    int r = (b << 9) + t;
    if (r < N_TOTAL) rowptr[r] = seg0 + excl;
    __syncthreads();
    for (int i = seg0 + t; i < seg1; i += BROWS) {
        uint2 p = packed0[i];
        int pos = seg0 + atomicAdd(&cur[p.x >> 18], 1);
        edges[pos] = make_uint2(p.x & 0x3FFFFu, p.y);
    }
}

// ---- convert original embeddings to bf16 layer-0 buffer ----
__global__ void convert_kernel(const float* __restrict__ ue, const float* __restrict__ ie,
                               u16* __restrict__ x) {
    int i = blockIdx.x * blockDim.x + threadIdx.x;
    if (i >= N_TOTAL * LATENT) return;
    float f = (i < NUM_USERS * LATENT) ? ue[i] : ie[i - NUM_USERS * LATENT];
    x[i] = f32_to_bf16(f);
}

// ---- shared row-SpMM core: lane l = edge slot (l>>4), dim quad (l&15)*4 ----
// returns acc[0..3] for dims q*4..q*4+3 where q=(l&15); valid on ALL lanes after shfl
__device__ __forceinline__ void spmm_row(const uint2* __restrict__ edges,
                                         const u16* __restrict__ x,
                                         int s, int e, int lane, float acc[4]) {
    int j = lane >> 4;          // edge sub-slot 0..3
    int q = (lane & 15) << 2;   // dim base
    acc[0] = acc[1] = acc[2] = acc[3] = 0.f;
    int i = s;
    for (; i + 8 <= e; i += 8) {
        uint2 e0 = edges[i + j];
        uint2 e1 = edges[i + 4 + j];
        uint2 x0 = *reinterpret_cast<const uint2*>(x + (size_t)e0.x * LATENT + q);
        uint2 x1 = *reinterpret_cast<const uint2*>(x + (size_t)e1.x * LATENT + q);
        float v0 = __uint_as_float(e0.y);
        float v1 = __uint_as_float(e1.y);
        acc[0] = fmaf(v0, bf16_lo(x0.x), acc[0]);
        acc[1] = fmaf(v0, bf16_hi(x0.x), acc[1]);
        acc[2] = fmaf(v0, bf16_lo(x0.y), acc[2]);
        acc[3] = fmaf(v0, bf16_hi(x0.y), acc[3]);
        acc[0] = fmaf(v1, bf16_lo(x1.x), acc[0]);
        acc[1] = fmaf(v1, bf16_hi(x1.x), acc[1]);
        acc[2] = fmaf(v1, bf16_lo(x1.y), acc[2]);
        acc[3] = fmaf(v1, bf16_hi(x1.y), acc[3]);
    }
    for (; i < e; i += 4) {
        // memory-safe: edges has >=4 zero-padded entries past nnz, and reading the
        // next row's edge is fine because v is forced to 0 for out-of-row slots
        uint2 e0 = edges[i + j];
        float v0 = (i + j < e) ? __uint_as_float(e0.y) : 0.f;
        uint2 x0 = *reinterpret_cast<const uint2*>(x + (size_t)e0.x * LATENT + q);
        acc[0] = fmaf(v0, bf16_lo(x0.x), acc[0]);
        acc[1] = fmaf(v0, bf16_hi(x0.x), acc[1]);
        acc[2] = fmaf(v0, bf16_lo(x0.y), acc[2]);
        acc[3] = fmaf(v0, bf16_hi(x0.y), acc[3]);
    }
    #pragma unroll
    for (int k = 0; k < 4; ++k) {
        acc[k] += __shfl_xor(acc[k], 16, 64);
        acc[k] += __shfl_xor(acc[k], 32, 64);
    }
}

// ---- full CSR SpMM: one wave per row, bf16 out ----
__global__ void spmm_kernel(const int* __restrict__ rowptr, const uint2* __restrict__ edges,
                            const u16* __restrict__ x, u16* __restrict__ y) {
    int row = blockIdx.x * 4 + (threadIdx.x >> 6);
    int lane = threadIdx.x & 63;
    int s = rowptr[row], e = rowptr[row + 1];
    float acc[4];
    spmm_row(edges, x, s, e, lane, acc);
    if (lane < 16) {
        u32 w0 = (u32)f32_to_bf16(acc[0]) | ((u32)f32_to_bf16(acc[1]) << 16);
        u32 w1 = (u32)f32_to_bf16(acc[2]) | ((u32)f32_to_bf16(acc[3]) << 16);
        *reinterpret_cast<uint2*>(y + (size_t)row * LATENT + (lane << 2)) = make_uint2(w0, w1);
    }
}

// ---- layer 3 fused: SpMM only for batch rows, accumulate into u_acc/i_acc ----
__global__ void spmm_batch_kernel(const int* __restrict__ rowptr, const uint2* __restrict__ edges,
                                  const u16* __restrict__ x,
                                  const int* __restrict__ users, const int* __restrict__ items,
                                  float* __restrict__ u_acc, float* __restrict__ i_acc) {
    int slot = blockIdx.x * 4 + (threadIdx.x >> 6);   // 0 .. 2*BATCH-1
    int lane = threadIdx.x & 63;
    int row = (slot < BATCH) ? users[slot] : (NUM_USERS + items[slot - BATCH]);
    int s = rowptr[row], e = rowptr[row + 1];
    float acc[4];
    spmm_row(edges, x, s, e, lane, acc);
    if (lane < 16) {
        float* dst = (slot < BATCH) ? (u_acc + (size_t)slot * LATENT)
                                    : (i_acc + (size_t)(slot - BATCH) * LATENT);
        float4* p = reinterpret_cast<float4*>(dst + (lane << 2));
        float4 old = *p;
        *p = make_float4(old.x + acc[0], old.y + acc[1], old.z + acc[2], old.w + acc[3]);
    }
}

// ---- init u_acc / i_acc from the raw f32 embeddings (layer-0 contribution) ----
__global__ void init_acc_kernel(const float* __restrict__ user_emb,
                                const float* __restrict__ item_emb,
                                const int* __restrict__ users,
                                const int* __restrict__ items,
                                float* __restrict__ u_acc,
                                float* __restrict__ i_acc) {
    int tid = blockIdx.x * blockDim.x + threadIdx.x;
    int b = tid >> 6, d = tid & 63;
    if (b >= BATCH) return;
    u_acc[tid] = user_emb[(size_t)users[b] * LATENT + d];
    i_acc[tid] = item_emb[(size_t)items[b] * LATENT + d];
}

// ---- accumulate gathered bf16 rows of the fresh layer (layers 1,2) ----
__global__ void gather_acc_kernel(const u16* __restrict__ emb,
                                  const int* __restrict__ users,
                                  const int* __restrict__ items,
                                  float* __restrict__ u_acc,
                                  float* __restrict__ i_acc) {
    int tid = blockIdx.x * blockDim.x + threadIdx.x;
    int b = tid >> 6, d = tid & 63;
    if (b >= BATCH) return;
    u_acc[tid] += __uint_as_float(((u32)emb[(size_t)users[b] * LATENT + d]) << 16);
    i_acc[tid] += __uint_as_float(((u32)emb[((size_t)items[b] + NUM_USERS) * LATENT + d]) << 16);
}

// ---- gamma[b] = dot(u_acc[b], i_acc[b]) / 16 ----
__global__ void dot_kernel(const float* __restrict__ u_acc,
                           const float* __restrict__ i_acc,
                           float* __restrict__ out) {
    int b = blockIdx.x;
    int d = threadIdx.x;  // 64 lanes = 1 wave
    float p = u_acc[b * 64 + d] * i_acc[b * 64 + d];
    #pragma unroll
    for (int off = 32; off; off >>= 1) p += __shfl_down(p, off, 64);
    if (d == 0) out[b] = p * (1.0f / 16.0f);
}

extern "C" void kernel_launch(void* const* d_in, const int* in_sizes, int n_in,
                              void* d_out, int out_size, void* d_ws, size_t ws_size,
                              hipStream_t stream) {
    const float* user_emb = (const float*)d_in[0];
    const float* item_emb = (const float*)d_in[1];
    const float* vals     = (const float*)d_in[2];
    const int*   rows     = (const int*)d_in[3];
    const int*   cols     = (const int*)d_in[4];
    const int*   users    = (const int*)d_in[5];
    const int*   items    = (const int*)d_in[6];
    float* out = (float*)d_out;

    const int nnz = in_sizes[2];

    char* ws = (char*)d_ws;
    const size_t embB  = (size_t)N_TOTAL * LATENT * sizeof(u16);     // 19.2 MB
    const size_t accB  = (size_t)BATCH * LATENT * sizeof(float);     // 4 MB
    const size_t edgeB = (size_t)(nnz + 8) * sizeof(uint2);          // 32 MB + pad

    size_t off = 0;
    u16*   emb_a   = (u16*)  (ws + off); off += embB;
    u16*   emb_b   = (u16*)  (ws + off); off += embB;
    uint2* packed0 = (uint2*)(ws + off); off += edgeB;
    uint2* edges   = (uint2*)(ws + off); off += edgeB;
    float* u_acc   = (float*)(ws + off); off += accB;
    float* i_acc   = (float*)(ws + off); off += accB;
    int*   rowptr  = (int*)  (ws + off); off += (size_t)(N_TOTAL + 1) * sizeof(int);
    int*   ccnt    = (int*)  (ws + off); off += (size_t)(NB + 1) * sizeof(int);
    int*   cptr    = (int*)  (ws + off); off += (size_t)(NB + 1) * sizeof(int);
    int*   ccur    = (int*)  (ws + off); off += (size_t)(NB + 1) * sizeof(int);

    // --- CSR build: coarse hist -> scan -> 2-level partition ---
    hipMemsetAsync(ccnt, 0, (size_t)(NB + 1) * sizeof(int), stream);
    hipMemsetAsync(edges + nnz, 0, 8 * sizeof(uint2), stream);   // tail padding
    coarse_hist_kernel<<<512, 256, 0, stream>>>(rows, ccnt, nnz);
    coarse_scan_kernel<<<1, 512, 0, stream>>>(ccnt, cptr, ccur, rowptr, nnz);
    partition1_kernel<<<512, 256, 0, stream>>>(rows, cols, vals, ccur, packed0, nnz);
    partition2_kernel<<<NB, BROWS, 0, stream>>>(cptr, packed0, edges, rowptr);

    convert_kernel<<<(N_TOTAL * LATENT + 255) / 256, 256, 0, stream>>>(user_emb, item_emb, emb_a);
    init_acc_kernel<<<(BATCH * 64) / 256, 256, 0, stream>>>(
        user_emb, item_emb, users, items, u_acc, i_acc);

    // layers 1 and 2: full SpMM (output feeds the next layer)
    u16* cur = emb_a;
    u16* nxt = emb_b;
    for (int l = 0; l < 2; ++l) {
        spmm_kernel<<<N_TOTAL / 4, 256, 0, stream>>>(rowptr, edges, cur, nxt);
        gather_acc_kernel<<<(BATCH * 64) / 256, 256, 0, stream>>>(
            nxt, users, items, u_acc, i_acc);
        u16* t = cur; cur = nxt; nxt = t;
    }

    // layer 3: only the 32768 batch rows, fused with the acc update
    spmm_batch_kernel<<<(2 * BATCH) / 4, 256, 0, stream>>>(
        rowptr, edges, cur, users, items, u_acc, i_acc);

    dot_kernel<<<BATCH, 64, 0, stream>>>(u_acc, i_acc, out);
}

// Round 5
// 345.827 us; speedup vs baseline: 29.3215x; 1.0801x over previous
//
#include <hip/hip_runtime.h>

#define NUM_USERS 100000
#define NUM_ITEMS 50000
#define N_TOTAL   150000
#define LATENT    64
#define BATCH     16384
#define BROWS     512                 // rows per coarse bucket
#define NB        293                 // ceil(N_TOTAL / BROWS)

typedef unsigned int u32;
typedef unsigned short u16;

__device__ __forceinline__ u16 f32_to_bf16(float f) {
    u32 u = __float_as_uint(f);
    u32 r = (u + 0x7FFFu + ((u >> 16) & 1u)) >> 16;   // round-to-nearest-even
    return (u16)r;
}
__device__ __forceinline__ float bf16_lo(u32 w) { return __uint_as_float(w << 16); }
__device__ __forceinline__ float bf16_hi(u32 w) { return __uint_as_float(w & 0xFFFF0000u); }

// ---- coarse histogram: bucket = row >> 9 ---- (512 threads: 8 waves/block)
__global__ void coarse_hist_kernel(const int* __restrict__ rows, int* __restrict__ ccnt, int nnz) {
    __shared__ int h[NB];
    for (int i = threadIdx.x; i < NB; i += blockDim.x) h[i] = 0;
    __syncthreads();
    int stride = gridDim.x * blockDim.x;
    for (int e = blockIdx.x * blockDim.x + threadIdx.x; e < nnz; e += stride)
        atomicAdd(&h[rows[e] >> 9], 1);
    __syncthreads();
    for (int i = threadIdx.x; i < NB; i += blockDim.x)
        if (h[i]) atomicAdd(&ccnt[i], h[i]);
}

// ---- scan 293 bucket counts -> coarse ptr + cursor; also rowptr[N_TOTAL] ----
__global__ void coarse_scan_kernel(const int* __restrict__ ccnt, int* __restrict__ cptr,
                                   int* __restrict__ ccur, int* __restrict__ rowptr, int nnz) {
    __shared__ int s[512];
    int t = threadIdx.x;
    int v = (t < NB) ? ccnt[t] : 0;
    s[t] = v;
    __syncthreads();
    for (int d = 1; d < 512; d <<= 1) {
        int x = (t >= d) ? s[t - d] : 0;
        __syncthreads();
        s[t] += x;
        __syncthreads();
    }
    int excl = s[t] - v;
    if (t < NB) { cptr[t] = excl; ccur[t] = excl; }
    if (t == 0) { cptr[NB] = nnz; rowptr[N_TOTAL] = nnz; }
}

// ---- pass 1: partition edges into coarse buckets (512 threads: 8 waves/block) ----
__global__ void partition1_kernel(const int* __restrict__ rows, const int* __restrict__ cols,
                                  const float* __restrict__ vals,
                                  int* __restrict__ ccur, uint2* __restrict__ packed0, int nnz) {
    __shared__ int lh[NB];
    __shared__ int lc[NB];
    int t = threadIdx.x;
    for (int i = t; i < NB; i += blockDim.x) lh[i] = 0;
    __syncthreads();
    int epb = (nnz + gridDim.x - 1) / gridDim.x;
    int s0 = blockIdx.x * epb;
    int s1 = s0 + epb; if (s1 > nnz) s1 = nnz;
    for (int e = s0 + t; e < s1; e += blockDim.x)
        atomicAdd(&lh[rows[e] >> 9], 1);
    __syncthreads();
    for (int i = t; i < NB; i += blockDim.x) {
        int c = lh[i];
        lc[i] = c ? atomicAdd(&ccur[i], c) : 0;
    }
    __syncthreads();
    for (int e = s0 + t; e < s1; e += blockDim.x) {
        int r = rows[e];
        int pos = atomicAdd(&lc[r >> 9], 1);
        packed0[pos] = make_uint2((u32)cols[e] | ((u32)(r & (BROWS - 1)) << 18),
                                  __float_as_uint(vals[e]));
    }
}

// ---- pass 2: per-bucket counting sort in LDS; emits rowptr + final edge list ----
// 2-stream unrolled loops for latency hiding (occupancy is bucket-bound at 29%)
__global__ void __launch_bounds__(BROWS)
partition2_kernel(const int* __restrict__ cptr, const uint2* __restrict__ packed0,
                  uint2* __restrict__ edges, int* __restrict__ rowptr) {
    __shared__ int cnt[BROWS];
    __shared__ int s[BROWS];
    __shared__ int cur[BROWS];
    int b = blockIdx.x;
    int t = threadIdx.x;
    int seg0 = cptr[b], seg1 = cptr[b + 1];
    cnt[t] = 0;
    __syncthreads();
    for (int i = seg0 + t; i < seg1; i += 2 * BROWS) {
        u32 k0 = packed0[i].x >> 18;
        int i2 = i + BROWS;
        if (i2 < seg1) {
            u32 k1 = packed0[i2].x >> 18;
            atomicAdd(&cnt[k0], 1);
            atomicAdd(&cnt[k1], 1);
        } else {
            atomicAdd(&cnt[k0], 1);
        }
    }
    __syncthreads();
    int v = cnt[t];
    s[t] = v;
    __syncthreads();
    for (int d = 1; d < BROWS; d <<= 1) {
        int x = (t >= d) ? s[t - d] : 0;
        __syncthreads();
        s[t] += x;
        __syncthreads();
    }
    int excl = s[t] - v;
    cur[t] = excl;
    int r = (b << 9) + t;
    if (r < N_TOTAL) rowptr[r] = seg0 + excl;
    __syncthreads();
    for (int i = seg0 + t; i < seg1; i += 2 * BROWS) {
        uint2 p0 = packed0[i];
        int i2 = i + BROWS;
        if (i2 < seg1) {
            uint2 p1 = packed0[i2];
            int pos0 = seg0 + atomicAdd(&cur[p0.x >> 18], 1);
            int pos1 = seg0 + atomicAdd(&cur[p1.x >> 18], 1);
            edges[pos0] = make_uint2(p0.x & 0x3FFFFu, p0.y);
            edges[pos1] = make_uint2(p1.x & 0x3FFFFu, p1.y);
        } else {
            int pos0 = seg0 + atomicAdd(&cur[p0.x >> 18], 1);
            edges[pos0] = make_uint2(p0.x & 0x3FFFFu, p0.y);
        }
    }
}

// ---- convert original embeddings to bf16 layer-0 buffer ----
__global__ void convert_kernel(const float* __restrict__ ue, const float* __restrict__ ie,
                               u16* __restrict__ x) {
    int i = blockIdx.x * blockDim.x + threadIdx.x;
    if (i >= N_TOTAL * LATENT) return;
    float f = (i < NUM_USERS * LATENT) ? ue[i] : ie[i - NUM_USERS * LATENT];
    x[i] = f32_to_bf16(f);
}

// ---- shared row-SpMM core: lane l = edge slot (l>>4), dim quad (l&15)*4 ----
// 16-edge main loop: 4 independent edge loads + 4 independent gathers in flight
__device__ __forceinline__ void spmm_row(const uint2* __restrict__ edges,
                                         const u16* __restrict__ x,
                                         int s, int e, int lane, float acc[4]) {
    int j = lane >> 4;          // edge sub-slot 0..3
    int q = (lane & 15) << 2;   // dim base
    acc[0] = acc[1] = acc[2] = acc[3] = 0.f;
    int i = s;
    for (; i + 16 <= e; i += 16) {
        uint2 e0 = edges[i + j];
        uint2 e1 = edges[i + 4 + j];
        uint2 e2 = edges[i + 8 + j];
        uint2 e3 = edges[i + 12 + j];
        uint2 x0 = *reinterpret_cast<const uint2*>(x + (size_t)e0.x * LATENT + q);
        uint2 x1 = *reinterpret_cast<const uint2*>(x + (size_t)e1.x * LATENT + q);
        uint2 x2 = *reinterpret_cast<const uint2*>(x + (size_t)e2.x * LATENT + q);
        uint2 x3 = *reinterpret_cast<const uint2*>(x + (size_t)e3.x * LATENT + q);
        float v0 = __uint_as_float(e0.y);
        float v1 = __uint_as_float(e1.y);
        float v2 = __uint_as_float(e2.y);
        float v3 = __uint_as_float(e3.y);
        acc[0] = fmaf(v0, bf16_lo(x0.x), acc[0]);
        acc[1] = fmaf(v0, bf16_hi(x0.x), acc[1]);
        acc[2] = fmaf(v0, bf16_lo(x0.y), acc[2]);
        acc[3] = fmaf(v0, bf16_hi(x0.y), acc[3]);
        acc[0] = fmaf(v1, bf16_lo(x1.x), acc[0]);
        acc[1] = fmaf(v1, bf16_hi(x1.x), acc[1]);
        acc[2] = fmaf(v1, bf16_lo(x1.y), acc[2]);
        acc[3] = fmaf(v1, bf16_hi(x1.y), acc[3]);
        acc[0] = fmaf(v2, bf16_lo(x2.x), acc[0]);
        acc[1] = fmaf(v2, bf16_hi(x2.x), acc[1]);
        acc[2] = fmaf(v2, bf16_lo(x2.y), acc[2]);
        acc[3] = fmaf(v2, bf16_hi(x2.y), acc[3]);
        acc[0] = fmaf(v3, bf16_lo(x3.x), acc[0]);
        acc[1] = fmaf(v3, bf16_hi(x3.x), acc[1]);
        acc[2] = fmaf(v3, bf16_lo(x3.y), acc[2]);
        acc[3] = fmaf(v3, bf16_hi(x3.y), acc[3]);
    }
    for (; i + 8 <= e; i += 8) {
        uint2 e0 = edges[i + j];
        uint2 e1 = edges[i + 4 + j];
        uint2 x0 = *reinterpret_cast<const uint2*>(x + (size_t)e0.x * LATENT + q);
        uint2 x1 = *reinterpret_cast<const uint2*>(x + (size_t)e1.x * LATENT + q);
        float v0 = __uint_as_float(e0.y);
        float v1 = __uint_as_float(e1.y);
        acc[0] = fmaf(v0, bf16_lo(x0.x), acc[0]);
        acc[1] = fmaf(v0, bf16_hi(x0.x), acc[1]);
        acc[2] = fmaf(v0, bf16_lo(x0.y), acc[2]);
        acc[3] = fmaf(v0, bf16_hi(x0.y), acc[3]);
        acc[0] = fmaf(v1, bf16_lo(x1.x), acc[0]);
        acc[1] = fmaf(v1, bf16_hi(x1.x), acc[1]);
        acc[2] = fmaf(v1, bf16_lo(x1.y), acc[2]);
        acc[3] = fmaf(v1, bf16_hi(x1.y), acc[3]);
    }
    for (; i < e; i += 4) {
        // memory-safe: edges has >=4 zero-padded entries past nnz; reading the
        // next row's edge is fine because v is forced to 0 for out-of-row slots
        uint2 e0 = edges[i + j];
        float v0 = (i + j < e) ? __uint_as_float(e0.y) : 0.f;
        uint2 x0 = *reinterpret_cast<const uint2*>(x + (size_t)e0.x * LATENT + q);
        acc[0] = fmaf(v0, bf16_lo(x0.x), acc[0]);
        acc[1] = fmaf(v0, bf16_hi(x0.x), acc[1]);
        acc[2] = fmaf(v0, bf16_lo(x0.y), acc[2]);
        acc[3] = fmaf(v0, bf16_hi(x0.y), acc[3]);
    }
    #pragma unroll
    for (int k = 0; k < 4; ++k) {
        acc[k] += __shfl_xor(acc[k], 16, 64);
        acc[k] += __shfl_xor(acc[k], 32, 64);
    }
}

// ---- full CSR SpMM: one wave per row, bf16 out ----
__global__ void spmm_kernel(const int* __restrict__ rowptr, const uint2* __restrict__ edges,
                            const u16* __restrict__ x, u16* __restrict__ y) {
    int row = blockIdx.x * 4 + (threadIdx.x >> 6);
    int lane = threadIdx.x & 63;
    int s = rowptr[row], e = rowptr[row + 1];
    float acc[4];
    spmm_row(edges, x, s, e, lane, acc);
    if (lane < 16) {
        u32 w0 = (u32)f32_to_bf16(acc[0]) | ((u32)f32_to_bf16(acc[1]) << 16);
        u32 w1 = (u32)f32_to_bf16(acc[2]) | ((u32)f32_to_bf16(acc[3]) << 16);
        *reinterpret_cast<uint2*>(y + (size_t)row * LATENT + (lane << 2)) = make_uint2(w0, w1);
    }
}

// ---- layer 3 fused: SpMM only for batch rows, accumulate into u_acc/i_acc ----
__global__ void spmm_batch_kernel(const int* __restrict__ rowptr, const uint2* __restrict__ edges,
                                  const u16* __restrict__ x,
                                  const int* __restrict__ users, const int* __restrict__ items,
                                  float* __restrict__ u_acc, float* __restrict__ i_acc) {
    int slot = blockIdx.x * 4 + (threadIdx.x >> 6);   // 0 .. 2*BATCH-1
    int lane = threadIdx.x & 63;
    int row = (slot < BATCH) ? users[slot] : (NUM_USERS + items[slot - BATCH]);
    int s = rowptr[row], e = rowptr[row + 1];
    float acc[4];
    spmm_row(edges, x, s, e, lane, acc);
    if (lane < 16) {
        float* dst = (slot < BATCH) ? (u_acc + (size_t)slot * LATENT)
                                    : (i_acc + (size_t)(slot - BATCH) * LATENT);
        float4* p = reinterpret_cast<float4*>(dst + (lane << 2));
        float4 old = *p;
        *p = make_float4(old.x + acc[0], old.y + acc[1], old.z + acc[2], old.w + acc[3]);
    }
}

// ---- init u_acc / i_acc from the raw f32 embeddings (layer-0 contribution) ----
__global__ void init_acc_kernel(const float* __restrict__ user_emb,
                                const float* __restrict__ item_emb,
                                const int* __restrict__ users,
                                const int* __restrict__ items,
                                float* __restrict__ u_acc,
                                float* __restrict__ i_acc) {
    int tid = blockIdx.x * blockDim.x + threadIdx.x;
    int b = tid >> 6, d = tid & 63;
    if (b >= BATCH) return;
    u_acc[tid] = user_emb[(size_t)users[b] * LATENT + d];
    i_acc[tid] = item_emb[(size_t)items[b] * LATENT + d];
}

// ---- accumulate gathered bf16 rows of the fresh layer (layers 1,2) ----
__global__ void gather_acc_kernel(const u16* __restrict__ emb,
                                  const int* __restrict__ users,
                                  const int* __restrict__ items,
                                  float* __restrict__ u_acc,
                                  float* __restrict__ i_acc) {
    int tid = blockIdx.x * blockDim.x + threadIdx.x;
    int b = tid >> 6, d = tid & 63;
    if (b >= BATCH) return;
    u_acc[tid] += __uint_as_float(((u32)emb[(size_t)users[b] * LATENT + d]) << 16);
    i_acc[tid] += __uint_as_float(((u32)emb[((size_t)items[b] + NUM_USERS) * LATENT + d]) << 16);
}

// ---- gamma[b] = dot(u_acc[b], i_acc[b]) / 16 ----
__global__ void dot_kernel(const float* __restrict__ u_acc,
                           const float* __restrict__ i_acc,
                           float* __restrict__ out) {
    int b = blockIdx.x;
    int d = threadIdx.x;  // 64 lanes = 1 wave
    float p = u_acc[b * 64 + d] * i_acc[b * 64 + d];
    #pragma unroll
    for (int off = 32; off; off >>= 1) p += __shfl_down(p, off, 64);
    if (d == 0) out[b] = p * (1.0f / 16.0f);
}

extern "C" void kernel_launch(void* const* d_in, const int* in_sizes, int n_in,
                              void* d_out, int out_size, void* d_ws, size_t ws_size,
                              hipStream_t stream) {
    const float* user_emb = (const float*)d_in[0];
    const float* item_emb = (const float*)d_in[1];
    const float* vals     = (const float*)d_in[2];
    const int*   rows     = (const int*)d_in[3];
    const int*   cols     = (const int*)d_in[4];
    const int*   users    = (const int*)d_in[5];
    const int*   items    = (const int*)d_in[6];
    float* out = (float*)d_out;

    const int nnz = in_sizes[2];

    char* ws = (char*)d_ws;
    const size_t embB  = (size_t)N_TOTAL * LATENT * sizeof(u16);     // 19.2 MB
    const size_t accB  = (size_t)BATCH * LATENT * sizeof(float);     // 4 MB
    const size_t edgeB = (size_t)(nnz + 16) * sizeof(uint2);         // 32 MB + pad

    size_t off = 0;
    u16*   emb_a   = (u16*)  (ws + off); off += embB;
    u16*   emb_b   = (u16*)  (ws + off); off += embB;
    uint2* packed0 = (uint2*)(ws + off); off += edgeB;
    uint2* edges   = (uint2*)(ws + off); off += edgeB;
    float* u_acc   = (float*)(ws + off); off += accB;
    float* i_acc   = (float*)(ws + off); off += accB;
    int*   rowptr  = (int*)  (ws + off); off += (size_t)(N_TOTAL + 1) * sizeof(int);
    int*   ccnt    = (int*)  (ws + off); off += (size_t)(NB + 1) * sizeof(int);
    int*   cptr    = (int*)  (ws + off); off += (size_t)(NB + 1) * sizeof(int);
    int*   ccur    = (int*)  (ws + off); off += (size_t)(NB + 1) * sizeof(int);

    // --- CSR build: coarse hist -> scan -> 2-level partition ---
    hipMemsetAsync(ccnt, 0, (size_t)(NB + 1) * sizeof(int), stream);
    hipMemsetAsync(edges + nnz, 0, 16 * sizeof(uint2), stream);   // tail padding
    coarse_hist_kernel<<<512, 512, 0, stream>>>(rows, ccnt, nnz);
    coarse_scan_kernel<<<1, 512, 0, stream>>>(ccnt, cptr, ccur, rowptr, nnz);
    partition1_kernel<<<512, 512, 0, stream>>>(rows, cols, vals, ccur, packed0, nnz);
    partition2_kernel<<<NB, BROWS, 0, stream>>>(cptr, packed0, edges, rowptr);

    convert_kernel<<<(N_TOTAL * LATENT + 255) / 256, 256, 0, stream>>>(user_emb, item_emb, emb_a);
    init_acc_kernel<<<(BATCH * 64) / 256, 256, 0, stream>>>(
        user_emb, item_emb, users, items, u_acc, i_acc);

    // layers 1 and 2: full SpMM (output feeds the next layer)
    u16* cur = emb_a;
    u16* nxt = emb_b;
    for (int l = 0; l < 2; ++l) {
        spmm_kernel<<<N_TOTAL / 4, 256, 0, stream>>>(rowptr, edges, cur, nxt);
        gather_acc_kernel<<<(BATCH * 64) / 256, 256, 0, stream>>>(
            nxt, users, items, u_acc, i_acc);
        u16* t = cur; cur = nxt; nxt = t;
    }

    // layer 3: only the 32768 batch rows, fused with the acc update
    spmm_batch_kernel<<<(2 * BATCH) / 4, 256, 0, stream>>>(
        rowptr, edges, cur, users, items, u_acc, i_acc);

    dot_kernel<<<BATCH, 64, 0, stream>>>(u_acc, i_acc, out);
}

// Round 6
// 336.418 us; speedup vs baseline: 30.1416x; 1.0280x over previous
//
#include <hip/hip_runtime.h>

#define NUM_USERS 100000
#define NUM_ITEMS 50000
#define N_TOTAL   150000
#define LATENT    64
#define BATCH     16384
#define BROWS     512                 // rows per coarse bucket
#define NB        293                 // ceil(N_TOTAL / BROWS)
#define P1_T      512                 // partition1 threads
#define P1_C      4096                // partition1 edges per block

typedef unsigned int u32;
typedef unsigned short u16;

__device__ __forceinline__ u16 f32_to_bf16(float f) {
    u32 u = __float_as_uint(f);
    u32 r = (u + 0x7FFFu + ((u >> 16) & 1u)) >> 16;   // round-to-nearest-even
    return (u16)r;
}
__device__ __forceinline__ float bf16_lo(u32 w) { return __uint_as_float(w << 16); }
__device__ __forceinline__ float bf16_hi(u32 w) { return __uint_as_float(w & 0xFFFF0000u); }

// ---- coarse histogram: bucket = row >> 9 ----
__global__ void coarse_hist_kernel(const int* __restrict__ rows, int* __restrict__ ccnt, int nnz) {
    __shared__ int h[NB];
    for (int i = threadIdx.x; i < NB; i += blockDim.x) h[i] = 0;
    __syncthreads();
    int stride = gridDim.x * blockDim.x;
    for (int e = blockIdx.x * blockDim.x + threadIdx.x; e < nnz; e += stride)
        atomicAdd(&h[rows[e] >> 9], 1);
    __syncthreads();
    for (int i = threadIdx.x; i < NB; i += blockDim.x)
        if (h[i]) atomicAdd(&ccnt[i], h[i]);
}

// ---- scan 293 bucket counts -> coarse ptr + cursor; also rowptr[N_TOTAL] ----
__global__ void coarse_scan_kernel(const int* __restrict__ ccnt, int* __restrict__ cptr,
                                   int* __restrict__ ccur, int* __restrict__ rowptr, int nnz) {
    __shared__ int s[512];
    int t = threadIdx.x;
    int v = (t < NB) ? ccnt[t] : 0;
    s[t] = v;
    __syncthreads();
    for (int d = 1; d < 512; d <<= 1) {
        int x = (t >= d) ? s[t - d] : 0;
        __syncthreads();
        s[t] += x;
        __syncthreads();
    }
    int excl = s[t] - v;
    if (t < NB) { cptr[t] = excl; ccur[t] = excl; }
    if (t == 0) { cptr[NB] = nnz; rowptr[N_TOTAL] = nnz; }
}

// ---- pass 1: chunk-local LDS counting sort by bucket, coalesced burst write-out ----
__global__ void __launch_bounds__(P1_T)
partition1_kernel(const int* __restrict__ rows, const int* __restrict__ cols,
                  const float* __restrict__ vals,
                  int* __restrict__ ccur, uint2* __restrict__ packed0, int nnz) {
    __shared__ u32 skey[P1_C];
    __shared__ u32 sval[P1_C];
    __shared__ u16 sbucket[P1_C];
    __shared__ int cnt[NB];
    __shared__ int lstart[NB];
    __shared__ int lcur[NB];
    __shared__ int gbase[NB];
    __shared__ int scanbuf[P1_T];

    int t = threadIdx.x;
    int base = blockIdx.x * P1_C;
    int chunkN = nnz - base; if (chunkN > P1_C) chunkN = P1_C;

    for (int i = t; i < NB; i += P1_T) cnt[i] = 0;
    __syncthreads();

    // Phase A: load up to 8 edges into registers, histogram buckets
    int   er[8]; u32 ek[8]; u32 ev[8];
    #pragma unroll
    for (int k = 0; k < 8; ++k) {
        int e = base + k * P1_T + t;
        bool ok = (k * P1_T + t) < chunkN;
        int r = ok ? rows[e] : 0;
        er[k] = ok ? (r >> 9) : -1;
        if (ok) {
            ek[k] = (u32)cols[e] | ((u32)(r & (BROWS - 1)) << 18);
            ev[k] = __float_as_uint(vals[e]);
            atomicAdd(&cnt[er[k]], 1);
        }
    }
    __syncthreads();

    // Phase B: scan the 293 counts; reserve global space per bucket
    int v = (t < NB) ? cnt[t] : 0;
    scanbuf[t] = v;
    __syncthreads();
    for (int d = 1; d < P1_T; d <<= 1) {
        int x = (t >= d) ? scanbuf[t - d] : 0;
        __syncthreads();
        scanbuf[t] += x;
        __syncthreads();
    }
    if (t < NB) {
        int excl = scanbuf[t] - v;
        lstart[t] = excl;
        lcur[t] = excl;
        gbase[t] = v ? atomicAdd(&ccur[t], v) : 0;
    }
    __syncthreads();

    // Phase C: scatter registers into LDS, sorted by bucket
    #pragma unroll
    for (int k = 0; k < 8; ++k) {
        if (er[k] >= 0) {
            int pos = atomicAdd(&lcur[er[k]], 1);
            skey[pos] = ek[k];
            sval[pos] = ev[k];
            sbucket[pos] = (u16)er[k];
        }
    }
    __syncthreads();

    // Phase D: burst write-out; consecutive threads -> consecutive global addrs per run
    for (int idx = t; idx < chunkN; idx += P1_T) {
        int b2 = sbucket[idx];
        int gp = gbase[b2] + (idx - lstart[b2]);
        packed0[gp] = make_uint2(skey[idx], sval[idx]);
    }
}

// ---- pass 2: per-bucket counting sort in LDS; emits rowptr + final edge list ----
__global__ void __launch_bounds__(BROWS)
partition2_kernel(const int* __restrict__ cptr, const uint2* __restrict__ packed0,
                  uint2* __restrict__ edges, int* __restrict__ rowptr) {
    __shared__ int cnt[BROWS];
    __shared__ int s[BROWS];
    __shared__ int cur[BROWS];
    int b = blockIdx.x;
    int t = threadIdx.x;
    int seg0 = cptr[b], seg1 = cptr[b + 1];
    cnt[t] = 0;
    __syncthreads();
    for (int i = seg0 + t; i < seg1; i += 2 * BROWS) {
        u32 k0 = packed0[i].x >> 18;
        int i2 = i + BROWS;
        if (i2 < seg1) {
            u32 k1 = packed0[i2].x >> 18;
            atomicAdd(&cnt[k0], 1);
            atomicAdd(&cnt[k1], 1);
        } else {
            atomicAdd(&cnt[k0], 1);
        }
    }
    __syncthreads();
    int v = cnt[t];
    s[t] = v;
    __syncthreads();
    for (int d = 1; d < BROWS; d <<= 1) {
        int x = (t >= d) ? s[t - d] : 0;
        __syncthreads();
        s[t] += x;
        __syncthreads();
    }
    int excl = s[t] - v;
    cur[t] = excl;
    int r = (b << 9) + t;
    if (r < N_TOTAL) rowptr[r] = seg0 + excl;
    __syncthreads();
    for (int i = seg0 + t; i < seg1; i += 2 * BROWS) {
        uint2 p0 = packed0[i];
        int i2 = i + BROWS;
        if (i2 < seg1) {
            uint2 p1 = packed0[i2];
            int pos0 = seg0 + atomicAdd(&cur[p0.x >> 18], 1);
            int pos1 = seg0 + atomicAdd(&cur[p1.x >> 18], 1);
            edges[pos0] = make_uint2(p0.x & 0x3FFFFu, p0.y);
            edges[pos1] = make_uint2(p1.x & 0x3FFFFu, p1.y);
        } else {
            int pos0 = seg0 + atomicAdd(&cur[p0.x >> 18], 1);
            edges[pos0] = make_uint2(p0.x & 0x3FFFFu, p0.y);
        }
    }
}

// ---- convert original embeddings to bf16 layer-0 buffer ----
__global__ void convert_kernel(const float* __restrict__ ue, const float* __restrict__ ie,
                               u16* __restrict__ x) {
    int i = blockIdx.x * blockDim.x + threadIdx.x;
    if (i >= N_TOTAL * LATENT) return;
    float f = (i < NUM_USERS * LATENT) ? ue[i] : ie[i - NUM_USERS * LATENT];
    x[i] = f32_to_bf16(f);
}

// ---- shared row-SpMM core: lane l = edge slot (l>>4), dim quad (l&15)*4 ----
__device__ __forceinline__ void spmm_row(const uint2* __restrict__ edges,
                                         const u16* __restrict__ x,
                                         int s, int e, int lane, float acc[4]) {
    int j = lane >> 4;          // edge sub-slot 0..3
    int q = (lane & 15) << 2;   // dim base
    acc[0] = acc[1] = acc[2] = acc[3] = 0.f;
    int i = s;
    for (; i + 16 <= e; i += 16) {
        uint2 e0 = edges[i + j];
        uint2 e1 = edges[i + 4 + j];
        uint2 e2 = edges[i + 8 + j];
        uint2 e3 = edges[i + 12 + j];
        uint2 x0 = *reinterpret_cast<const uint2*>(x + (size_t)e0.x * LATENT + q);
        uint2 x1 = *reinterpret_cast<const uint2*>(x + (size_t)e1.x * LATENT + q);
        uint2 x2 = *reinterpret_cast<const uint2*>(x + (size_t)e2.x * LATENT + q);
        uint2 x3 = *reinterpret_cast<const uint2*>(x + (size_t)e3.x * LATENT + q);
        float v0 = __uint_as_float(e0.y);
        float v1 = __uint_as_float(e1.y);
        float v2 = __uint_as_float(e2.y);
        float v3 = __uint_as_float(e3.y);
        acc[0] = fmaf(v0, bf16_lo(x0.x), acc[0]);
        acc[1] = fmaf(v0, bf16_hi(x0.x), acc[1]);
        acc[2] = fmaf(v0, bf16_lo(x0.y), acc[2]);
        acc[3] = fmaf(v0, bf16_hi(x0.y), acc[3]);
        acc[0] = fmaf(v1, bf16_lo(x1.x), acc[0]);
        acc[1] = fmaf(v1, bf16_hi(x1.x), acc[1]);
        acc[2] = fmaf(v1, bf16_lo(x1.y), acc[2]);
        acc[3] = fmaf(v1, bf16_hi(x1.y), acc[3]);
        acc[0] = fmaf(v2, bf16_lo(x2.x), acc[0]);
        acc[1] = fmaf(v2, bf16_hi(x2.x), acc[1]);
        acc[2] = fmaf(v2, bf16_lo(x2.y), acc[2]);
        acc[3] = fmaf(v2, bf16_hi(x2.y), acc[3]);
        acc[0] = fmaf(v3, bf16_lo(x3.x), acc[0]);
        acc[1] = fmaf(v3, bf16_hi(x3.x), acc[1]);
        acc[2] = fmaf(v3, bf16_lo(x3.y), acc[2]);
        acc[3] = fmaf(v3, bf16_hi(x3.y), acc[3]);
    }
    for (; i + 8 <= e; i += 8) {
        uint2 e0 = edges[i + j];
        uint2 e1 = edges[i + 4 + j];
        uint2 x0 = *reinterpret_cast<const uint2*>(x + (size_t)e0.x * LATENT + q);
        uint2 x1 = *reinterpret_cast<const uint2*>(x + (size_t)e1.x * LATENT + q);
        float v0 = __uint_as_float(e0.y);
        float v1 = __uint_as_float(e1.y);
        acc[0] = fmaf(v0, bf16_lo(x0.x), acc[0]);
        acc[1] = fmaf(v0, bf16_hi(x0.x), acc[1]);
        acc[2] = fmaf(v0, bf16_lo(x0.y), acc[2]);
        acc[3] = fmaf(v0, bf16_hi(x0.y), acc[3]);
        acc[0] = fmaf(v1, bf16_lo(x1.x), acc[0]);
        acc[1] = fmaf(v1, bf16_hi(x1.x), acc[1]);
        acc[2] = fmaf(v1, bf16_lo(x1.y), acc[2]);
        acc[3] = fmaf(v1, bf16_hi(x1.y), acc[3]);
    }
    for (; i < e; i += 4) {
        // memory-safe: edges has >=16 zero-padded entries past nnz; reading the
        // next row's edge is fine because v is forced to 0 for out-of-row slots
        uint2 e0 = edges[i + j];
        float v0 = (i + j < e) ? __uint_as_float(e0.y) : 0.f;
        uint2 x0 = *reinterpret_cast<const uint2*>(x + (size_t)e0.x * LATENT + q);
        acc[0] = fmaf(v0, bf16_lo(x0.x), acc[0]);
        acc[1] = fmaf(v0, bf16_hi(x0.x), acc[1]);
        acc[2] = fmaf(v0, bf16_lo(x0.y), acc[2]);
        acc[3] = fmaf(v0, bf16_hi(x0.y), acc[3]);
    }
    #pragma unroll
    for (int k = 0; k < 4; ++k) {
        acc[k] += __shfl_xor(acc[k], 16, 64);
        acc[k] += __shfl_xor(acc[k], 32, 64);
    }
}

// ---- full CSR SpMM: one wave per row, bf16 out ----
__global__ void spmm_kernel(const int* __restrict__ rowptr, const uint2* __restrict__ edges,
                            const u16* __restrict__ x, u16* __restrict__ y) {
    int row = blockIdx.x * 4 + (threadIdx.x >> 6);
    int lane = threadIdx.x & 63;
    int s = rowptr[row], e = rowptr[row + 1];
    float acc[4];
    spmm_row(edges, x, s, e, lane, acc);
    if (lane < 16) {
        u32 w0 = (u32)f32_to_bf16(acc[0]) | ((u32)f32_to_bf16(acc[1]) << 16);
        u32 w1 = (u32)f32_to_bf16(acc[2]) | ((u32)f32_to_bf16(acc[3]) << 16);
        *reinterpret_cast<uint2*>(y + (size_t)row * LATENT + (lane << 2)) = make_uint2(w0, w1);
    }
}

// ---- layer 3 fused: SpMM only for batch rows, accumulate into u_acc/i_acc ----
__global__ void spmm_batch_kernel(const int* __restrict__ rowptr, const uint2* __restrict__ edges,
                                  const u16* __restrict__ x,
                                  const int* __restrict__ users, const int* __restrict__ items,
                                  float* __restrict__ u_acc, float* __restrict__ i_acc) {
    int slot = blockIdx.x * 4 + (threadIdx.x >> 6);   // 0 .. 2*BATCH-1
    int lane = threadIdx.x & 63;
    int row = (slot < BATCH) ? users[slot] : (NUM_USERS + items[slot - BATCH]);
    int s = rowptr[row], e = rowptr[row + 1];
    float acc[4];
    spmm_row(edges, x, s, e, lane, acc);
    if (lane < 16) {
        float* dst = (slot < BATCH) ? (u_acc + (size_t)slot * LATENT)
                                    : (i_acc + (size_t)(slot - BATCH) * LATENT);
        float4* p = reinterpret_cast<float4*>(dst + (lane << 2));
        float4 old = *p;
        *p = make_float4(old.x + acc[0], old.y + acc[1], old.z + acc[2], old.w + acc[3]);
    }
}

// ---- init u_acc / i_acc from the raw f32 embeddings (layer-0 contribution) ----
__global__ void init_acc_kernel(const float* __restrict__ user_emb,
                                const float* __restrict__ item_emb,
                                const int* __restrict__ users,
                                const int* __restrict__ items,
                                float* __restrict__ u_acc,
                                float* __restrict__ i_acc) {
    int tid = blockIdx.x * blockDim.x + threadIdx.x;
    int b = tid >> 6, d = tid & 63;
    if (b >= BATCH) return;
    u_acc[tid] = user_emb[(size_t)users[b] * LATENT + d];
    i_acc[tid] = item_emb[(size_t)items[b] * LATENT + d];
}

// ---- accumulate gathered bf16 rows of the fresh layer (layers 1,2) ----
__global__ void gather_acc_kernel(const u16* __restrict__ emb,
                                  const int* __restrict__ users,
                                  const int* __restrict__ items,
                                  float* __restrict__ u_acc,
                                  float* __restrict__ i_acc) {
    int tid = blockIdx.x * blockDim.x + threadIdx.x;
    int b = tid >> 6, d = tid & 63;
    if (b >= BATCH) return;
    u_acc[tid] += __uint_as_float(((u32)emb[(size_t)users[b] * LATENT + d]) << 16);
    i_acc[tid] += __uint_as_float(((u32)emb[((size_t)items[b] + NUM_USERS) * LATENT + d]) << 16);
}

// ---- gamma[b] = dot(u_acc[b], i_acc[b]) / 16 ----
__global__ void dot_kernel(const float* __restrict__ u_acc,
                           const float* __restrict__ i_acc,
                           float* __restrict__ out) {
    int b = blockIdx.x;
    int d = threadIdx.x;  // 64 lanes = 1 wave
    float p = u_acc[b * 64 + d] * i_acc[b * 64 + d];
    #pragma unroll
    for (int off = 32; off; off >>= 1) p += __shfl_down(p, off, 64);
    if (d == 0) out[b] = p * (1.0f / 16.0f);
}

extern "C" void kernel_launch(void* const* d_in, const int* in_sizes, int n_in,
                              void* d_out, int out_size, void* d_ws, size_t ws_size,
                              hipStream_t stream) {
    const float* user_emb = (const float*)d_in[0];
    const float* item_emb = (const float*)d_in[1];
    const float* vals     = (const float*)d_in[2];
    const int*   rows     = (const int*)d_in[3];
    const int*   cols     = (const int*)d_in[4];
    const int*   users    = (const int*)d_in[5];
    const int*   items    = (const int*)d_in[6];
    float* out = (float*)d_out;

    const int nnz = in_sizes[2];

    char* ws = (char*)d_ws;
    const size_t embB  = (size_t)N_TOTAL * LATENT * sizeof(u16);     // 19.2 MB
    const size_t accB  = (size_t)BATCH * LATENT * sizeof(float);     // 4 MB
    const size_t edgeB = (size_t)(nnz + 16) * sizeof(uint2);         // 32 MB + pad

    size_t off = 0;
    u16*   emb_a   = (u16*)  (ws + off); off += embB;
    u16*   emb_b   = (u16*)  (ws + off); off += embB;
    uint2* packed0 = (uint2*)(ws + off); off += edgeB;
    uint2* edges   = (uint2*)(ws + off); off += edgeB;
    float* u_acc   = (float*)(ws + off); off += accB;
    float* i_acc   = (float*)(ws + off); off += accB;
    int*   rowptr  = (int*)  (ws + off); off += (size_t)(N_TOTAL + 1) * sizeof(int);
    int*   ccnt    = (int*)  (ws + off); off += (size_t)(NB + 1) * sizeof(int);
    int*   cptr    = (int*)  (ws + off); off += (size_t)(NB + 1) * sizeof(int);
    int*   ccur    = (int*)  (ws + off); off += (size_t)(NB + 1) * sizeof(int);

    // --- CSR build: coarse hist -> scan -> 2-level partition ---
    hipMemsetAsync(ccnt, 0, (size_t)(NB + 1) * sizeof(int), stream);
    hipMemsetAsync(edges + nnz, 0, 16 * sizeof(uint2), stream);   // tail padding
    coarse_hist_kernel<<<512, 512, 0, stream>>>(rows, ccnt, nnz);
    coarse_scan_kernel<<<1, 512, 0, stream>>>(ccnt, cptr, ccur, rowptr, nnz);
    partition1_kernel<<<(nnz + P1_C - 1) / P1_C, P1_T, 0, stream>>>(
        rows, cols, vals, ccur, packed0, nnz);
    partition2_kernel<<<NB, BROWS, 0, stream>>>(cptr, packed0, edges, rowptr);

    convert_kernel<<<(N_TOTAL * LATENT + 255) / 256, 256, 0, stream>>>(user_emb, item_emb, emb_a);
    init_acc_kernel<<<(BATCH * 64) / 256, 256, 0, stream>>>(
        user_emb, item_emb, users, items, u_acc, i_acc);

    // layers 1 and 2: full SpMM (output feeds the next layer)
    u16* cur = emb_a;
    u16* nxt = emb_b;
    for (int l = 0; l < 2; ++l) {
        spmm_kernel<<<N_TOTAL / 4, 256, 0, stream>>>(rowptr, edges, cur, nxt);
        gather_acc_kernel<<<(BATCH * 64) / 256, 256, 0, stream>>>(
            nxt, users, items, u_acc, i_acc);
        u16* t = cur; cur = nxt; nxt = t;
    }

    // layer 3: only the 32768 batch rows, fused with the acc update
    spmm_batch_kernel<<<(2 * BATCH) / 4, 256, 0, stream>>>(
        rowptr, edges, cur, users, items, u_acc, i_acc);

    dot_kernel<<<BATCH, 64, 0, stream>>>(u_acc, i_acc, out);
}

// Round 7
// 311.884 us; speedup vs baseline: 32.5126x; 1.0787x over previous
//
#include <hip/hip_runtime.h>

#define NUM_USERS 100000
#define NUM_ITEMS 50000
#define N_TOTAL   150000
#define LATENT    64
#define BATCH     16384
#define BROWS     512                 // rows per coarse bucket
#define NB        293                 // ceil(N_TOTAL / BROWS)
#define CAP       16384               // per-bucket slab capacity (count ~13.6k +- 120)
#define P1_T      512                 // partition1 threads
#define P1_C      4096                // partition1 edges per block

typedef unsigned int u32;
typedef unsigned short u16;

__device__ __forceinline__ u16 f32_to_bf16(float f) {
    u32 u = __float_as_uint(f);
    u32 r = (u + 0x7FFFu + ((u >> 16) & 1u)) >> 16;   // round-to-nearest-even
    return (u16)r;
}
__device__ __forceinline__ float bf16_lo(u32 w) { return __uint_as_float(w << 16); }
__device__ __forceinline__ float bf16_hi(u32 w) { return __uint_as_float(w & 0xFFFF0000u); }

__device__ __forceinline__ void fma4(float acc[4], uint2 xv, float v) {
    acc[0] = fmaf(v, bf16_lo(xv.x), acc[0]);
    acc[1] = fmaf(v, bf16_hi(xv.x), acc[1]);
    acc[2] = fmaf(v, bf16_lo(xv.y), acc[2]);
    acc[3] = fmaf(v, bf16_hi(xv.y), acc[3]);
}

// ---- pass 1: chunk-local LDS counting sort by bucket, burst write into capacity slabs ----
// bucket cursors (ccur) are zero-initialized; no pre-histogram needed.
__global__ void __launch_bounds__(P1_T)
partition1_kernel(const int* __restrict__ rows, const int* __restrict__ cols,
                  const float* __restrict__ vals,
                  int* __restrict__ ccur, uint2* __restrict__ packed0, int nnz) {
    __shared__ u32 skey[P1_C];
    __shared__ u32 sval[P1_C];
    __shared__ u16 sbucket[P1_C];
    __shared__ int cnt[NB];
    __shared__ int lstart[NB];
    __shared__ int lcur[NB];
    __shared__ int gbase[NB];
    __shared__ int scanbuf[P1_T];

    int t = threadIdx.x;
    int base = blockIdx.x * P1_C;
    int chunkN = nnz - base; if (chunkN > P1_C) chunkN = P1_C;

    for (int i = t; i < NB; i += P1_T) cnt[i] = 0;
    __syncthreads();

    // Phase A: load up to 8 edges into registers, histogram buckets
    int er[8]; u32 ek[8]; u32 ev[8];
    #pragma unroll
    for (int k = 0; k < 8; ++k) {
        int e = base + k * P1_T + t;
        bool ok = (k * P1_T + t) < chunkN;
        int r = ok ? rows[e] : 0;
        er[k] = ok ? (r >> 9) : -1;
        if (ok) {
            ek[k] = (u32)cols[e] | ((u32)(r & (BROWS - 1)) << 18);
            ev[k] = __float_as_uint(vals[e]);
            atomicAdd(&cnt[er[k]], 1);
        }
    }
    __syncthreads();

    // Phase B: scan the 293 counts; reserve slab space per bucket
    int v = (t < NB) ? cnt[t] : 0;
    scanbuf[t] = v;
    __syncthreads();
    for (int d = 1; d < P1_T; d <<= 1) {
        int x = (t >= d) ? scanbuf[t - d] : 0;
        __syncthreads();
        scanbuf[t] += x;
        __syncthreads();
    }
    if (t < NB) {
        int excl = scanbuf[t] - v;
        lstart[t] = excl;
        lcur[t] = excl;
        gbase[t] = v ? atomicAdd(&ccur[t], v) : 0;
    }
    __syncthreads();

    // Phase C: scatter registers into LDS, sorted by bucket
    #pragma unroll
    for (int k = 0; k < 8; ++k) {
        if (er[k] >= 0) {
            int pos = atomicAdd(&lcur[er[k]], 1);
            skey[pos] = ek[k];
            sval[pos] = ev[k];
            sbucket[pos] = (u16)er[k];
        }
    }
    __syncthreads();

    // Phase D: burst write-out into slab packed0[bucket*CAP + ...]
    for (int idx = t; idx < chunkN; idx += P1_T) {
        int b2 = sbucket[idx];
        size_t gp = (size_t)b2 * CAP + gbase[b2] + (idx - lstart[b2]);
        packed0[gp] = make_uint2(skey[idx], sval[idx]);
    }
}

// ---- scan 293 bucket counts -> compact output offsets cptr; rowptr tail ----
__global__ void bucket_scan_kernel(const int* __restrict__ ccur, int* __restrict__ cptr,
                                   int* __restrict__ rowptr, int nnz) {
    __shared__ int s[512];
    int t = threadIdx.x;
    int v = (t < NB) ? ccur[t] : 0;
    s[t] = v;
    __syncthreads();
    for (int d = 1; d < 512; d <<= 1) {
        int x = (t >= d) ? s[t - d] : 0;
        __syncthreads();
        s[t] += x;
        __syncthreads();
    }
    if (t < NB) cptr[t] = s[t] - v;
    if (t == 0) { cptr[NB] = nnz; rowptr[N_TOTAL] = nnz; }
}

// ---- pass 2: per-bucket counting sort in LDS; emits rowptr + final compact edge list ----
__global__ void __launch_bounds__(BROWS)
partition2_kernel(const int* __restrict__ cptr, const uint2* __restrict__ packed0,
                  uint2* __restrict__ edges, int* __restrict__ rowptr) {
    __shared__ int cnt[BROWS];
    __shared__ int s[BROWS];
    __shared__ int cur[BROWS];
    int b = blockIdx.x;
    int t = threadIdx.x;
    const uint2* src = packed0 + (size_t)b * CAP;
    int outb = cptr[b];
    int count = cptr[b + 1] - outb;
    cnt[t] = 0;
    __syncthreads();
    for (int i = t; i < count; i += 2 * BROWS) {
        u32 k0 = src[i].x >> 18;
        int i2 = i + BROWS;
        if (i2 < count) {
            u32 k1 = src[i2].x >> 18;
            atomicAdd(&cnt[k0], 1);
            atomicAdd(&cnt[k1], 1);
        } else {
            atomicAdd(&cnt[k0], 1);
        }
    }
    __syncthreads();
    int v = cnt[t];
    s[t] = v;
    __syncthreads();
    for (int d = 1; d < BROWS; d <<= 1) {
        int x = (t >= d) ? s[t - d] : 0;
        __syncthreads();
        s[t] += x;
        __syncthreads();
    }
    int excl = s[t] - v;
    cur[t] = excl;
    int r = (b << 9) + t;
    if (r < N_TOTAL) rowptr[r] = outb + excl;
    __syncthreads();
    for (int i = t; i < count; i += 2 * BROWS) {
        uint2 p0 = src[i];
        int i2 = i + BROWS;
        if (i2 < count) {
            uint2 p1 = src[i2];
            int pos0 = outb + atomicAdd(&cur[p0.x >> 18], 1);
            int pos1 = outb + atomicAdd(&cur[p1.x >> 18], 1);
            edges[pos0] = make_uint2(p0.x & 0x3FFFFu, p0.y);
            edges[pos1] = make_uint2(p1.x & 0x3FFFFu, p1.y);
        } else {
            int pos0 = outb + atomicAdd(&cur[p0.x >> 18], 1);
            edges[pos0] = make_uint2(p0.x & 0x3FFFFu, p0.y);
        }
    }
}

// ---- convert original embeddings to bf16 layer-0 buffer ----
__global__ void convert_kernel(const float* __restrict__ ue, const float* __restrict__ ie,
                               u16* __restrict__ x) {
    int i = blockIdx.x * blockDim.x + threadIdx.x;
    if (i >= N_TOTAL * LATENT) return;
    float f = (i < NUM_USERS * LATENT) ? ue[i] : ie[i - NUM_USERS * LATENT];
    x[i] = f32_to_bf16(f);
}

// ---- row tail: 8-edge then guarded 4-edge loops (no reduce) ----
__device__ __forceinline__ void row_tail(const uint2* __restrict__ edges,
                                         const u16* __restrict__ x,
                                         int i, int e, int j, int q, float acc[4]) {
    for (; i + 8 <= e; i += 8) {
        uint2 e0 = edges[i + j];
        uint2 e1 = edges[i + 4 + j];
        uint2 x0 = *reinterpret_cast<const uint2*>(x + (size_t)e0.x * LATENT + q);
        uint2 x1 = *reinterpret_cast<const uint2*>(x + (size_t)e1.x * LATENT + q);
        fma4(acc, x0, __uint_as_float(e0.y));
        fma4(acc, x1, __uint_as_float(e1.y));
    }
    for (; i < e; i += 4) {
        // memory-safe: edges has >=16 zero-padded entries past nnz; reading the
        // next row's edge is fine because v is forced to 0 for out-of-row slots
        uint2 e0 = edges[i + j];
        float v0 = (i + j < e) ? __uint_as_float(e0.y) : 0.f;
        uint2 x0 = *reinterpret_cast<const uint2*>(x + (size_t)e0.x * LATENT + q);
        fma4(acc, x0, v0);
    }
}

// ---- single-row SpMM core (used by batch kernel) ----
__device__ __forceinline__ void spmm_row(const uint2* __restrict__ edges,
                                         const u16* __restrict__ x,
                                         int s, int e, int lane, float acc[4]) {
    int j = lane >> 4;
    int q = (lane & 15) << 2;
    acc[0] = acc[1] = acc[2] = acc[3] = 0.f;
    int i = s;
    for (; i + 16 <= e; i += 16) {
        uint2 e0 = edges[i + j];
        uint2 e1 = edges[i + 4 + j];
        uint2 e2 = edges[i + 8 + j];
        uint2 e3 = edges[i + 12 + j];
        uint2 x0 = *reinterpret_cast<const uint2*>(x + (size_t)e0.x * LATENT + q);
        uint2 x1 = *reinterpret_cast<const uint2*>(x + (size_t)e1.x * LATENT + q);
        uint2 x2 = *reinterpret_cast<const uint2*>(x + (size_t)e2.x * LATENT + q);
        uint2 x3 = *reinterpret_cast<const uint2*>(x + (size_t)e3.x * LATENT + q);
        fma4(acc, x0, __uint_as_float(e0.y));
        fma4(acc, x1, __uint_as_float(e1.y));
        fma4(acc, x2, __uint_as_float(e2.y));
        fma4(acc, x3, __uint_as_float(e3.y));
    }
    row_tail(edges, x, i, e, j, q, acc);
    #pragma unroll
    for (int k = 0; k < 4; ++k) {
        acc[k] += __shfl_xor(acc[k], 16, 64);
        acc[k] += __shfl_xor(acc[k], 32, 64);
    }
}

// ---- full CSR SpMM: one wave per TWO adjacent rows (two independent load chains) ----
__global__ void spmm_kernel(const int* __restrict__ rowptr, const uint2* __restrict__ edges,
                            const u16* __restrict__ x, u16* __restrict__ y) {
    int wid = blockIdx.x * 4 + (threadIdx.x >> 6);
    int r0 = wid * 2;
    int lane = threadIdx.x & 63;
    int j = lane >> 4;
    int q = (lane & 15) << 2;
    int i0 = rowptr[r0];
    int e0 = rowptr[r0 + 1];
    int i1 = e0;                       // CSR: row r0+1 starts where r0 ends
    int e1 = rowptr[r0 + 2];
    float a0[4] = {0.f, 0.f, 0.f, 0.f};
    float a1[4] = {0.f, 0.f, 0.f, 0.f};

    // joint phase: two independent 8-edge chains in flight
    while (i0 + 8 <= e0 && i1 + 8 <= e1) {
        uint2 p00 = edges[i0 + j];
        uint2 p01 = edges[i0 + 4 + j];
        uint2 p10 = edges[i1 + j];
        uint2 p11 = edges[i1 + 4 + j];
        uint2 g00 = *reinterpret_cast<const uint2*>(x + (size_t)p00.x * LATENT + q);
        uint2 g01 = *reinterpret_cast<const uint2*>(x + (size_t)p01.x * LATENT + q);
        uint2 g10 = *reinterpret_cast<const uint2*>(x + (size_t)p10.x * LATENT + q);
        uint2 g11 = *reinterpret_cast<const uint2*>(x + (size_t)p11.x * LATENT + q);
        fma4(a0, g00, __uint_as_float(p00.y));
        fma4(a0, g01, __uint_as_float(p01.y));
        fma4(a1, g10, __uint_as_float(p10.y));
        fma4(a1, g11, __uint_as_float(p11.y));
        i0 += 8;
        i1 += 8;
    }
    row_tail(edges, x, i0, e0, j, q, a0);
    row_tail(edges, x, i1, e1, j, q, a1);

    #pragma unroll
    for (int k = 0; k < 4; ++k) {
        a0[k] += __shfl_xor(a0[k], 16, 64);
        a0[k] += __shfl_xor(a0[k], 32, 64);
        a1[k] += __shfl_xor(a1[k], 16, 64);
        a1[k] += __shfl_xor(a1[k], 32, 64);
    }
    if (lane < 16) {
        u32 w0 = (u32)f32_to_bf16(a0[0]) | ((u32)f32_to_bf16(a0[1]) << 16);
        u32 w1 = (u32)f32_to_bf16(a0[2]) | ((u32)f32_to_bf16(a0[3]) << 16);
        *reinterpret_cast<uint2*>(y + (size_t)r0 * LATENT + (lane << 2)) = make_uint2(w0, w1);
        u32 w2 = (u32)f32_to_bf16(a1[0]) | ((u32)f32_to_bf16(a1[1]) << 16);
        u32 w3 = (u32)f32_to_bf16(a1[2]) | ((u32)f32_to_bf16(a1[3]) << 16);
        *reinterpret_cast<uint2*>(y + (size_t)(r0 + 1) * LATENT + (lane << 2)) = make_uint2(w2, w3);
    }
}

// ---- layer 3 fused: SpMM only for batch rows, accumulate into u_acc/i_acc ----
__global__ void spmm_batch_kernel(const int* __restrict__ rowptr, const uint2* __restrict__ edges,
                                  const u16* __restrict__ x,
                                  const int* __restrict__ users, const int* __restrict__ items,
                                  float* __restrict__ u_acc, float* __restrict__ i_acc) {
    int slot = blockIdx.x * 4 + (threadIdx.x >> 6);   // 0 .. 2*BATCH-1
    int lane = threadIdx.x & 63;
    int row = (slot < BATCH) ? users[slot] : (NUM_USERS + items[slot - BATCH]);
    int s = rowptr[row], e = rowptr[row + 1];
    float acc[4];
    spmm_row(edges, x, s, e, lane, acc);
    if (lane < 16) {
        float* dst = (slot < BATCH) ? (u_acc + (size_t)slot * LATENT)
                                    : (i_acc + (size_t)(slot - BATCH) * LATENT);
        float4* p = reinterpret_cast<float4*>(dst + (lane << 2));
        float4 old = *p;
        *p = make_float4(old.x + acc[0], old.y + acc[1], old.z + acc[2], old.w + acc[3]);
    }
}

// ---- init u_acc / i_acc from the raw f32 embeddings (layer-0 contribution) ----
__global__ void init_acc_kernel(const float* __restrict__ user_emb,
                                const float* __restrict__ item_emb,
                                const int* __restrict__ users,
                                const int* __restrict__ items,
                                float* __restrict__ u_acc,
                                float* __restrict__ i_acc) {
    int tid = blockIdx.x * blockDim.x + threadIdx.x;
    int b = tid >> 6, d = tid & 63;
    if (b >= BATCH) return;
    u_acc[tid] = user_emb[(size_t)users[b] * LATENT + d];
    i_acc[tid] = item_emb[(size_t)items[b] * LATENT + d];
}

// ---- accumulate gathered bf16 rows of the fresh layer (layers 1,2) ----
__global__ void gather_acc_kernel(const u16* __restrict__ emb,
                                  const int* __restrict__ users,
                                  const int* __restrict__ items,
                                  float* __restrict__ u_acc,
                                  float* __restrict__ i_acc) {
    int tid = blockIdx.x * blockDim.x + threadIdx.x;
    int b = tid >> 6, d = tid & 63;
    if (b >= BATCH) return;
    u_acc[tid] += __uint_as_float(((u32)emb[(size_t)users[b] * LATENT + d]) << 16);
    i_acc[tid] += __uint_as_float(((u32)emb[((size_t)items[b] + NUM_USERS) * LATENT + d]) << 16);
}

// ---- gamma[b] = dot(u_acc[b], i_acc[b]) / 16 ----
__global__ void dot_kernel(const float* __restrict__ u_acc,
                           const float* __restrict__ i_acc,
                           float* __restrict__ out) {
    int b = blockIdx.x;
    int d = threadIdx.x;  // 64 lanes = 1 wave
    float p = u_acc[b * 64 + d] * i_acc[b * 64 + d];
    #pragma unroll
    for (int off = 32; off; off >>= 1) p += __shfl_down(p, off, 64);
    if (d == 0) out[b] = p * (1.0f / 16.0f);
}

extern "C" void kernel_launch(void* const* d_in, const int* in_sizes, int n_in,
                              void* d_out, int out_size, void* d_ws, size_t ws_size,
                              hipStream_t stream) {
    const float* user_emb = (const float*)d_in[0];
    const float* item_emb = (const float*)d_in[1];
    const float* vals     = (const float*)d_in[2];
    const int*   rows     = (const int*)d_in[3];
    const int*   cols     = (const int*)d_in[4];
    const int*   users    = (const int*)d_in[5];
    const int*   items    = (const int*)d_in[6];
    float* out = (float*)d_out;

    const int nnz = in_sizes[2];

    char* ws = (char*)d_ws;
    const size_t embB   = (size_t)N_TOTAL * LATENT * sizeof(u16);     // 19.2 MB
    const size_t accB   = (size_t)BATCH * LATENT * sizeof(float);     // 4 MB
    const size_t slabB  = (size_t)NB * CAP * sizeof(uint2);           // 38.4 MB
    const size_t edgeB  = (size_t)(nnz + 16) * sizeof(uint2);         // 32 MB + pad

    size_t off = 0;
    u16*   emb_a   = (u16*)  (ws + off); off += embB;
    u16*   emb_b   = (u16*)  (ws + off); off += embB;
    uint2* packed0 = (uint2*)(ws + off); off += slabB;
    uint2* edges   = (uint2*)(ws + off); off += edgeB;
    float* u_acc   = (float*)(ws + off); off += accB;
    float* i_acc   = (float*)(ws + off); off += accB;
    int*   rowptr  = (int*)  (ws + off); off += (size_t)(N_TOTAL + 1) * sizeof(int);
    int*   ccur    = (int*)  (ws + off); off += (size_t)(NB + 1) * sizeof(int);
    int*   cptr    = (int*)  (ws + off); off += (size_t)(NB + 1) * sizeof(int);

    // --- CSR build: capacity-slab partition (no pre-histogram) ---
    hipMemsetAsync(ccur, 0, (size_t)(NB + 1) * sizeof(int), stream);
    hipMemsetAsync(edges + nnz, 0, 16 * sizeof(uint2), stream);   // tail padding
    partition1_kernel<<<(nnz + P1_C - 1) / P1_C, P1_T, 0, stream>>>(
        rows, cols, vals, ccur, packed0, nnz);
    bucket_scan_kernel<<<1, 512, 0, stream>>>(ccur, cptr, rowptr, nnz);
    partition2_kernel<<<NB, BROWS, 0, stream>>>(cptr, packed0, edges, rowptr);

    convert_kernel<<<(N_TOTAL * LATENT + 255) / 256, 256, 0, stream>>>(user_emb, item_emb, emb_a);
    init_acc_kernel<<<(BATCH * 64) / 256, 256, 0, stream>>>(
        user_emb, item_emb, users, items, u_acc, i_acc);

    // layers 1 and 2: full SpMM (output feeds the next layer), 2 rows per wave
    u16* cur = emb_a;
    u16* nxt = emb_b;
    for (int l = 0; l < 2; ++l) {
        spmm_kernel<<<N_TOTAL / 8, 256, 0, stream>>>(rowptr, edges, cur, nxt);
        gather_acc_kernel<<<(BATCH * 64) / 256, 256, 0, stream>>>(
            nxt, users, items, u_acc, i_acc);
        u16* t = cur; cur = nxt; nxt = t;
    }

    // layer 3: only the 32768 batch rows, fused with the acc update
    spmm_batch_kernel<<<(2 * BATCH) / 4, 256, 0, stream>>>(
        rowptr, edges, cur, users, items, u_acc, i_acc);

    dot_kernel<<<BATCH, 64, 0, stream>>>(u_acc, i_acc, out);
}

// Round 8
// 304.736 us; speedup vs baseline: 33.2752x; 1.0235x over previous
//
#include <hip/hip_runtime.h>

#define NUM_USERS 100000
#define NUM_ITEMS 50000
#define N_TOTAL   150000
#define LATENT    64
#define BATCH     16384
#define BROWS     512                 // rows per coarse bucket
#define NB        293                 // ceil(N_TOTAL / BROWS)
#define CAP       16384               // per-bucket slab capacity (count ~13.6k +- 120)
#define P1_T      512                 // partition1 threads
#define P1_C      4096                // partition1 edges per block

typedef unsigned int u32;
typedef unsigned short u16;

__device__ __forceinline__ u16 f32_to_bf16(float f) {
    u32 u = __float_as_uint(f);
    u32 r = (u + 0x7FFFu + ((u >> 16) & 1u)) >> 16;   // round-to-nearest-even
    return (u16)r;
}
__device__ __forceinline__ float bf16_lo(u32 w) { return __uint_as_float(w << 16); }
__device__ __forceinline__ float bf16_hi(u32 w) { return __uint_as_float(w & 0xFFFF0000u); }

__device__ __forceinline__ void fma4(float acc[4], uint2 xv, float v) {
    acc[0] = fmaf(v, bf16_lo(xv.x), acc[0]);
    acc[1] = fmaf(v, bf16_hi(xv.x), acc[1]);
    acc[2] = fmaf(v, bf16_lo(xv.y), acc[2]);
    acc[3] = fmaf(v, bf16_hi(xv.y), acc[3]);
}

// ---- wave-level inclusive scan (64 lanes) ----
__device__ __forceinline__ int wave_incl_scan(int v, int lane) {
    #pragma unroll
    for (int d = 1; d < 64; d <<= 1) {
        int t = __shfl_up(v, d, 64);
        if (lane >= d) v += t;
    }
    return v;
}

// ---- 512-thread block exclusive scan; wsum is LDS int[8]; 2 barriers ----
__device__ __forceinline__ int block_excl_scan_512(int v, int t, int* wsum) {
    int lane = t & 63, w = t >> 6;
    int incl = wave_incl_scan(v, lane);
    if (lane == 63) wsum[w] = incl;
    __syncthreads();
    if (t == 0) {
        int acc = 0;
        #pragma unroll
        for (int k = 0; k < 8; ++k) { int c = wsum[k]; wsum[k] = acc; acc += c; }
    }
    __syncthreads();
    return wsum[w] + incl - v;
}

// ---- pass 1: chunk-local LDS counting sort by bucket, burst write into capacity slabs ----
__global__ void __launch_bounds__(P1_T)
partition1_kernel(const int* __restrict__ rows, const int* __restrict__ cols,
                  const float* __restrict__ vals,
                  int* __restrict__ ccur, uint2* __restrict__ packed0,
                  u16* __restrict__ klab, int nnz) {
    __shared__ u32 skey[P1_C];
    __shared__ u32 sval[P1_C];
    __shared__ u16 sbucket[P1_C];
    __shared__ int cnt[NB];
    __shared__ int lstart[NB];
    __shared__ int lcur[NB];
    __shared__ int gbase[NB];
    __shared__ int wsum[8];

    int t = threadIdx.x;
    int base = blockIdx.x * P1_C;
    int chunkN = nnz - base; if (chunkN > P1_C) chunkN = P1_C;

    for (int i = t; i < NB; i += P1_T) cnt[i] = 0;
    __syncthreads();

    // Phase A: load up to 8 edges into registers, histogram buckets
    int er[8]; u32 ek[8]; u32 ev[8];
    #pragma unroll
    for (int k = 0; k < 8; ++k) {
        int e = base + k * P1_T + t;
        bool ok = (k * P1_T + t) < chunkN;
        int r = ok ? rows[e] : 0;
        er[k] = ok ? (r >> 9) : -1;
        if (ok) {
            ek[k] = (u32)cols[e] | ((u32)(r & (BROWS - 1)) << 18);
            ev[k] = __float_as_uint(vals[e]);
            atomicAdd(&cnt[er[k]], 1);
        }
    }
    __syncthreads();

    // Phase B: wave-scan the 293 counts; reserve slab space per bucket
    int v = (t < NB) ? cnt[t] : 0;
    int excl = block_excl_scan_512(v, t, wsum);
    if (t < NB) {
        lstart[t] = excl;
        lcur[t] = excl;
        gbase[t] = v ? atomicAdd(&ccur[t], v) : 0;
    }
    __syncthreads();

    // Phase C: scatter registers into LDS, sorted by bucket
    #pragma unroll
    for (int k = 0; k < 8; ++k) {
        if (er[k] >= 0) {
            int pos = atomicAdd(&lcur[er[k]], 1);
            skey[pos] = ek[k];
            sval[pos] = ev[k];
            sbucket[pos] = (u16)er[k];
        }
    }
    __syncthreads();

    // Phase D: burst write-out into slab packed0[bucket*CAP + ...] (+ compact key slab)
    for (int idx = t; idx < chunkN; idx += P1_T) {
        int b2 = sbucket[idx];
        size_t gp = (size_t)b2 * CAP + gbase[b2] + (idx - lstart[b2]);
        u32 key = skey[idx];
        packed0[gp] = make_uint2(key, sval[idx]);
        klab[gp] = (u16)(key >> 18);
    }
}

// ---- scan 293 bucket counts -> compact output offsets cptr; rowptr tail ----
__global__ void bucket_scan_kernel(const int* __restrict__ ccur, int* __restrict__ cptr,
                                   int* __restrict__ rowptr, int nnz) {
    __shared__ int wsum[8];
    int t = threadIdx.x;
    int v = (t < NB) ? ccur[t] : 0;
    int excl = block_excl_scan_512(v, t, wsum);
    if (t < NB) cptr[t] = excl;
    if (t == 0) { cptr[NB] = nnz; rowptr[N_TOTAL] = nnz; }
}

// ---- pass 2: per-bucket counting sort in LDS; emits rowptr + final compact edge list ----
__global__ void __launch_bounds__(BROWS)
partition2_kernel(const int* __restrict__ cptr, const uint2* __restrict__ packed0,
                  const u16* __restrict__ klab,
                  uint2* __restrict__ edges, int* __restrict__ rowptr) {
    __shared__ int cnt[BROWS];
    __shared__ int cur[BROWS];
    __shared__ int wsum[8];
    int b = blockIdx.x;
    int t = threadIdx.x;
    const uint2* src = packed0 + (size_t)b * CAP;
    const u16*   kl  = klab + (size_t)b * CAP;
    int outb = cptr[b];
    int count = cptr[b + 1] - outb;
    cnt[t] = 0;
    __syncthreads();
    // histogram from the compact 2B key stream
    for (int i = t; i < count; i += 2 * BROWS) {
        u16 k0 = kl[i];
        int i2 = i + BROWS;
        if (i2 < count) {
            u16 k1 = kl[i2];
            atomicAdd(&cnt[k0], 1);
            atomicAdd(&cnt[k1], 1);
        } else {
            atomicAdd(&cnt[k0], 1);
        }
    }
    __syncthreads();
    int v = cnt[t];
    int excl = block_excl_scan_512(v, t, wsum);
    cur[t] = excl;
    int r = (b << 9) + t;
    if (r < N_TOTAL) rowptr[r] = outb + excl;
    __syncthreads();
    for (int i = t; i < count; i += 2 * BROWS) {
        uint2 p0 = src[i];
        int i2 = i + BROWS;
        if (i2 < count) {
            uint2 p1 = src[i2];
            int pos0 = outb + atomicAdd(&cur[p0.x >> 18], 1);
            int pos1 = outb + atomicAdd(&cur[p1.x >> 18], 1);
            edges[pos0] = make_uint2(p0.x & 0x3FFFFu, p0.y);
            edges[pos1] = make_uint2(p1.x & 0x3FFFFu, p1.y);
        } else {
            int pos0 = outb + atomicAdd(&cur[p0.x >> 18], 1);
            edges[pos0] = make_uint2(p0.x & 0x3FFFFu, p0.y);
        }
    }
}

// ---- convert original embeddings to bf16 layer-0 buffer (float4 / ushort4) ----
__global__ void convert_kernel(const float* __restrict__ ue, const float* __restrict__ ie,
                               u16* __restrict__ x) {
    int i = blockIdx.x * blockDim.x + threadIdx.x;       // group of 4 elements
    const int n4 = N_TOTAL * LATENT / 4;
    const int ub = NUM_USERS * LATENT / 4;
    if (i >= n4) return;
    float4 f = (i < ub) ? reinterpret_cast<const float4*>(ue)[i]
                        : reinterpret_cast<const float4*>(ie)[i - ub];
    ushort4 o;
    o.x = f32_to_bf16(f.x); o.y = f32_to_bf16(f.y);
    o.z = f32_to_bf16(f.z); o.w = f32_to_bf16(f.w);
    reinterpret_cast<ushort4*>(x)[i] = o;
}

// ---- row tail: 8-edge then guarded 4-edge loops (no reduce) ----
__device__ __forceinline__ void row_tail(const uint2* __restrict__ edges,
                                         const u16* __restrict__ x,
                                         int i, int e, int j, int q, float acc[4]) {
    for (; i + 8 <= e; i += 8) {
        uint2 e0 = edges[i + j];
        uint2 e1 = edges[i + 4 + j];
        uint2 x0 = *reinterpret_cast<const uint2*>(x + (size_t)e0.x * LATENT + q);
        uint2 x1 = *reinterpret_cast<const uint2*>(x + (size_t)e1.x * LATENT + q);
        fma4(acc, x0, __uint_as_float(e0.y));
        fma4(acc, x1, __uint_as_float(e1.y));
    }
    for (; i < e; i += 4) {
        // memory-safe: edges has >=16 zero-padded entries past nnz; reading the
        // next row's edge is fine because v is forced to 0 for out-of-row slots
        uint2 e0 = edges[i + j];
        float v0 = (i + j < e) ? __uint_as_float(e0.y) : 0.f;
        uint2 x0 = *reinterpret_cast<const uint2*>(x + (size_t)e0.x * LATENT + q);
        fma4(acc, x0, v0);
    }
}

// ---- single-row SpMM core (used by batch kernel) ----
__device__ __forceinline__ void spmm_row(const uint2* __restrict__ edges,
                                         const u16* __restrict__ x,
                                         int s, int e, int lane, float acc[4]) {
    int j = lane >> 4;
    int q = (lane & 15) << 2;
    acc[0] = acc[1] = acc[2] = acc[3] = 0.f;
    int i = s;
    for (; i + 16 <= e; i += 16) {
        uint2 e0 = edges[i + j];
        uint2 e1 = edges[i + 4 + j];
        uint2 e2 = edges[i + 8 + j];
        uint2 e3 = edges[i + 12 + j];
        uint2 x0 = *reinterpret_cast<const uint2*>(x + (size_t)e0.x * LATENT + q);
        uint2 x1 = *reinterpret_cast<const uint2*>(x + (size_t)e1.x * LATENT + q);
        uint2 x2 = *reinterpret_cast<const uint2*>(x + (size_t)e2.x * LATENT + q);
        uint2 x3 = *reinterpret_cast<const uint2*>(x + (size_t)e3.x * LATENT + q);
        fma4(acc, x0, __uint_as_float(e0.y));
        fma4(acc, x1, __uint_as_float(e1.y));
        fma4(acc, x2, __uint_as_float(e2.y));
        fma4(acc, x3, __uint_as_float(e3.y));
    }
    row_tail(edges, x, i, e, j, q, acc);
    #pragma unroll
    for (int k = 0; k < 4; ++k) {
        acc[k] += __shfl_xor(acc[k], 16, 64);
        acc[k] += __shfl_xor(acc[k], 32, 64);
    }
}

// ---- full CSR SpMM: one wave per TWO adjacent rows (two independent load chains) ----
__global__ void spmm_kernel(const int* __restrict__ rowptr, const uint2* __restrict__ edges,
                            const u16* __restrict__ x, u16* __restrict__ y) {
    int wid = blockIdx.x * 4 + (threadIdx.x >> 6);
    int r0 = wid * 2;
    int lane = threadIdx.x & 63;
    int j = lane >> 4;
    int q = (lane & 15) << 2;
    int i0 = rowptr[r0];
    int e0 = rowptr[r0 + 1];
    int i1 = e0;
    int e1 = rowptr[r0 + 2];
    float a0[4] = {0.f, 0.f, 0.f, 0.f};
    float a1[4] = {0.f, 0.f, 0.f, 0.f};

    while (i0 + 8 <= e0 && i1 + 8 <= e1) {
        uint2 p00 = edges[i0 + j];
        uint2 p01 = edges[i0 + 4 + j];
        uint2 p10 = edges[i1 + j];
        uint2 p11 = edges[i1 + 4 + j];
        uint2 g00 = *reinterpret_cast<const uint2*>(x + (size_t)p00.x * LATENT + q);
        uint2 g01 = *reinterpret_cast<const uint2*>(x + (size_t)p01.x * LATENT + q);
        uint2 g10 = *reinterpret_cast<const uint2*>(x + (size_t)p10.x * LATENT + q);
        uint2 g11 = *reinterpret_cast<const uint2*>(x + (size_t)p11.x * LATENT + q);
        fma4(a0, g00, __uint_as_float(p00.y));
        fma4(a0, g01, __uint_as_float(p01.y));
        fma4(a1, g10, __uint_as_float(p10.y));
        fma4(a1, g11, __uint_as_float(p11.y));
        i0 += 8;
        i1 += 8;
    }
    row_tail(edges, x, i0, e0, j, q, a0);
    row_tail(edges, x, i1, e1, j, q, a1);

    #pragma unroll
    for (int k = 0; k < 4; ++k) {
        a0[k] += __shfl_xor(a0[k], 16, 64);
        a0[k] += __shfl_xor(a0[k], 32, 64);
        a1[k] += __shfl_xor(a1[k], 16, 64);
        a1[k] += __shfl_xor(a1[k], 32, 64);
    }
    if (lane < 16) {
        u32 w0 = (u32)f32_to_bf16(a0[0]) | ((u32)f32_to_bf16(a0[1]) << 16);
        u32 w1 = (u32)f32_to_bf16(a0[2]) | ((u32)f32_to_bf16(a0[3]) << 16);
        *reinterpret_cast<uint2*>(y + (size_t)r0 * LATENT + (lane << 2)) = make_uint2(w0, w1);
        u32 w2 = (u32)f32_to_bf16(a1[0]) | ((u32)f32_to_bf16(a1[1]) << 16);
        u32 w3 = (u32)f32_to_bf16(a1[2]) | ((u32)f32_to_bf16(a1[3]) << 16);
        *reinterpret_cast<uint2*>(y + (size_t)(r0 + 1) * LATENT + (lane << 2)) = make_uint2(w2, w3);
    }
}

// ---- layer 3 fused: SpMM only for batch rows, accumulate into u_acc/i_acc ----
__global__ void spmm_batch_kernel(const int* __restrict__ rowptr, const uint2* __restrict__ edges,
                                  const u16* __restrict__ x,
                                  const int* __restrict__ users, const int* __restrict__ items,
                                  float* __restrict__ u_acc, float* __restrict__ i_acc) {
    int slot = blockIdx.x * 4 + (threadIdx.x >> 6);   // 0 .. 2*BATCH-1
    int lane = threadIdx.x & 63;
    int row = (slot < BATCH) ? users[slot] : (NUM_USERS + items[slot - BATCH]);
    int s = rowptr[row], e = rowptr[row + 1];
    float acc[4];
    spmm_row(edges, x, s, e, lane, acc);
    if (lane < 16) {
        float* dst = (slot < BATCH) ? (u_acc + (size_t)slot * LATENT)
                                    : (i_acc + (size_t)(slot - BATCH) * LATENT);
        float4* p = reinterpret_cast<float4*>(dst + (lane << 2));
        float4 old = *p;
        *p = make_float4(old.x + acc[0], old.y + acc[1], old.z + acc[2], old.w + acc[3]);
    }
}

// ---- init u_acc / i_acc from the raw f32 embeddings (layer-0 contribution) ----
__global__ void init_acc_kernel(const float* __restrict__ user_emb,
                                const float* __restrict__ item_emb,
                                const int* __restrict__ users,
                                const int* __restrict__ items,
                                float* __restrict__ u_acc,
                                float* __restrict__ i_acc) {
    int tid = blockIdx.x * blockDim.x + threadIdx.x;
    int b = tid >> 6, d = tid & 63;
    if (b >= BATCH) return;
    u_acc[tid] = user_emb[(size_t)users[b] * LATENT + d];
    i_acc[tid] = item_emb[(size_t)items[b] * LATENT + d];
}

// ---- accumulate gathered bf16 rows of the fresh layer (layers 1,2) ----
__global__ void gather_acc_kernel(const u16* __restrict__ emb,
                                  const int* __restrict__ users,
                                  const int* __restrict__ items,
                                  float* __restrict__ u_acc,
                                  float* __restrict__ i_acc) {
    int tid = blockIdx.x * blockDim.x + threadIdx.x;
    int b = tid >> 6, d = tid & 63;
    if (b >= BATCH) return;
    u_acc[tid] += __uint_as_float(((u32)emb[(size_t)users[b] * LATENT + d]) << 16);
    i_acc[tid] += __uint_as_float(((u32)emb[((size_t)items[b] + NUM_USERS) * LATENT + d]) << 16);
}

// ---- gamma[b] = dot(u_acc[b], i_acc[b]) / 16 ----
__global__ void dot_kernel(const float* __restrict__ u_acc,
                           const float* __restrict__ i_acc,
                           float* __restrict__ out) {
    int b = blockIdx.x;
    int d = threadIdx.x;  // 64 lanes = 1 wave
    float p = u_acc[b * 64 + d] * i_acc[b * 64 + d];
    #pragma unroll
    for (int off = 32; off; off >>= 1) p += __shfl_down(p, off, 64);
    if (d == 0) out[b] = p * (1.0f / 16.0f);
}

extern "C" void kernel_launch(void* const* d_in, const int* in_sizes, int n_in,
                              void* d_out, int out_size, void* d_ws, size_t ws_size,
                              hipStream_t stream) {
    const float* user_emb = (const float*)d_in[0];
    const float* item_emb = (const float*)d_in[1];
    const float* vals     = (const float*)d_in[2];
    const int*   rows     = (const int*)d_in[3];
    const int*   cols     = (const int*)d_in[4];
    const int*   users    = (const int*)d_in[5];
    const int*   items    = (const int*)d_in[6];
    float* out = (float*)d_out;

    const int nnz = in_sizes[2];

    char* ws = (char*)d_ws;
    const size_t embB   = (size_t)N_TOTAL * LATENT * sizeof(u16);     // 19.2 MB
    const size_t accB   = (size_t)BATCH * LATENT * sizeof(float);     // 4 MB
    const size_t slabB  = (size_t)NB * CAP * sizeof(uint2);           // 38.4 MB
    const size_t klabB  = (size_t)NB * CAP * sizeof(u16);             // 9.6 MB
    const size_t edgeB  = (size_t)(nnz + 16) * sizeof(uint2);         // 32 MB + pad

    size_t off = 0;
    u16*   emb_a   = (u16*)  (ws + off); off += embB;
    u16*   emb_b   = (u16*)  (ws + off); off += embB;
    uint2* packed0 = (uint2*)(ws + off); off += slabB;
    u16*   klab    = (u16*)  (ws + off); off += klabB;
    uint2* edges   = (uint2*)(ws + off); off += edgeB;
    float* u_acc   = (float*)(ws + off); off += accB;
    float* i_acc   = (float*)(ws + off); off += accB;
    int*   rowptr  = (int*)  (ws + off); off += (size_t)(N_TOTAL + 1) * sizeof(int);
    int*   ccur    = (int*)  (ws + off); off += (size_t)(NB + 1) * sizeof(int);
    int*   cptr    = (int*)  (ws + off); off += (size_t)(NB + 1) * sizeof(int);

    // --- CSR build: capacity-slab partition (no pre-histogram) ---
    hipMemsetAsync(ccur, 0, (size_t)(NB + 1) * sizeof(int), stream);
    hipMemsetAsync(edges + nnz, 0, 16 * sizeof(uint2), stream);   // tail padding
    partition1_kernel<<<(nnz + P1_C - 1) / P1_C, P1_T, 0, stream>>>(
        rows, cols, vals, ccur, packed0, klab, nnz);
    bucket_scan_kernel<<<1, 512, 0, stream>>>(ccur, cptr, rowptr, nnz);
    partition2_kernel<<<NB, BROWS, 0, stream>>>(cptr, packed0, klab, edges, rowptr);

    convert_kernel<<<(N_TOTAL * LATENT / 4 + 255) / 256, 256, 0, stream>>>(
        user_emb, item_emb, emb_a);
    init_acc_kernel<<<(BATCH * 64) / 256, 256, 0, stream>>>(
        user_emb, item_emb, users, items, u_acc, i_acc);

    // layers 1 and 2: full SpMM (output feeds the next layer), 2 rows per wave
    u16* cur = emb_a;
    u16* nxt = emb_b;
    for (int l = 0; l < 2; ++l) {
        spmm_kernel<<<N_TOTAL / 8, 256, 0, stream>>>(rowptr, edges, cur, nxt);
        gather_acc_kernel<<<(BATCH * 64) / 256, 256, 0, stream>>>(
            nxt, users, items, u_acc, i_acc);
        u16* t = cur; cur = nxt; nxt = t;
    }

    // layer 3: only the 32768 batch rows, fused with the acc update
    spmm_batch_kernel<<<(2 * BATCH) / 4, 256, 0, stream>>>(
        rowptr, edges, cur, users, items, u_acc, i_acc);

    dot_kernel<<<BATCH, 64, 0, stream>>>(u_acc, i_acc, out);
}

// Round 10
// 287.337 us; speedup vs baseline: 35.2901x; 1.0606x over previous
//
#include <hip/hip_runtime.h>

#define NUM_USERS 100000
#define NUM_ITEMS 50000
#define N_TOTAL   150000
#define LATENT    64
#define BATCH     16384
#define BROWS     512                 // rows per coarse bucket
#define NB        293                 // ceil(N_TOTAL / BROWS)
#define CAP       16384               // per-bucket slab capacity (count ~13.6k +- 120, +23 sigma)
#define P1_T      512                 // partition threads
#define P1_C      4096                // partition1 edges per block
#define CVT_B     2344                // convert blocks (2.4M float4 items, 2/thread)
#define INIT_B    512                 // init_acc blocks (BATCH*16 float4 threads)
#define GATH_B    1024                // gather blocks (BATCH*16 threads @256)

typedef unsigned int u32;
typedef unsigned short u16;

__device__ __forceinline__ u16 f32_to_bf16(float f) {
    u32 u = __float_as_uint(f);
    u32 r = (u + 0x7FFFu + ((u >> 16) & 1u)) >> 16;   // round-to-nearest-even
    return (u16)r;
}
__device__ __forceinline__ float bf16_lo(u32 w) { return __uint_as_float(w << 16); }
__device__ __forceinline__ float bf16_hi(u32 w) { return __uint_as_float(w & 0xFFFF0000u); }

__device__ __forceinline__ void fma4(float acc[4], uint2 xv, float v) {
    acc[0] = fmaf(v, bf16_lo(xv.x), acc[0]);
    acc[1] = fmaf(v, bf16_hi(xv.x), acc[1]);
    acc[2] = fmaf(v, bf16_lo(xv.y), acc[2]);
    acc[3] = fmaf(v, bf16_hi(xv.y), acc[3]);
}

// ---- wave-level inclusive scan (64 lanes) ----
__device__ __forceinline__ int wave_incl_scan(int v, int lane) {
    #pragma unroll
    for (int d = 1; d < 64; d <<= 1) {
        int t = __shfl_up(v, d, 64);
        if (lane >= d) v += t;
    }
    return v;
}

// ---- 512-thread block exclusive scan; wsum is LDS int[8]; 2 barriers ----
__device__ __forceinline__ int block_excl_scan_512(int v, int t, int* wsum) {
    int lane = t & 63, w = t >> 6;
    int incl = wave_incl_scan(v, lane);
    if (lane == 63) wsum[w] = incl;
    __syncthreads();
    if (t == 0) {
        int acc = 0;
        #pragma unroll
        for (int k = 0; k < 8; ++k) { int c = wsum[k]; wsum[k] = acc; acc += c; }
    }
    __syncthreads();
    return wsum[w] + incl - v;
}

// =================== fat kernel A: partition1 | convert | init_acc ===================
__global__ void __launch_bounds__(P1_T)
fatA_kernel(const int* __restrict__ rows, const int* __restrict__ cols,
            const float* __restrict__ vals,
            int* __restrict__ ccur, uint2* __restrict__ packed0, u16* __restrict__ klab,
            const float* __restrict__ ue, const float* __restrict__ ie,
            u16* __restrict__ emb0,
            const int* __restrict__ users, const int* __restrict__ items,
            float* __restrict__ u_acc, float* __restrict__ i_acc,
            int nnz, int np1) {
    __shared__ u32 skey[P1_C];
    __shared__ u32 sval[P1_C];
    __shared__ u16 sbucket[P1_C];
    __shared__ int cnt[NB];
    __shared__ int lstart[NB];
    __shared__ int lcur[NB];
    __shared__ int gbase[NB];
    __shared__ int wsum[8];

    int t = threadIdx.x;
    int bid = blockIdx.x;

    if (bid < np1) {
        // ---------------- partition1 role ----------------
        int base = bid * P1_C;
        int chunkN = nnz - base; if (chunkN > P1_C) chunkN = P1_C;

        for (int i = t; i < NB; i += P1_T) cnt[i] = 0;
        __syncthreads();

        int er[8]; u32 ek[8]; u32 ev[8];
        #pragma unroll
        for (int k = 0; k < 8; ++k) {
            int e = base + k * P1_T + t;
            bool ok = (k * P1_T + t) < chunkN;
            int r = ok ? rows[e] : 0;
            er[k] = ok ? (r >> 9) : -1;
            if (ok) {
                ek[k] = (u32)cols[e] | ((u32)(r & (BROWS - 1)) << 18);
                ev[k] = __float_as_uint(vals[e]);
                atomicAdd(&cnt[er[k]], 1);
            }
        }
        __syncthreads();

        int v = (t < NB) ? cnt[t] : 0;
        int excl = block_excl_scan_512(v, t, wsum);
        if (t < NB) {
            lstart[t] = excl;
            lcur[t] = excl;
            gbase[t] = v ? atomicAdd(&ccur[t], v) : 0;
        }
        __syncthreads();

        #pragma unroll
        for (int k = 0; k < 8; ++k) {
            if (er[k] >= 0) {
                int pos = atomicAdd(&lcur[er[k]], 1);
                skey[pos] = ek[k];
                sval[pos] = ev[k];
                sbucket[pos] = (u16)er[k];
            }
        }
        __syncthreads();

        for (int idx = t; idx < chunkN; idx += P1_T) {
            int b2 = sbucket[idx];
            size_t gp = (size_t)b2 * CAP + gbase[b2] + (idx - lstart[b2]);
            u32 key = skey[idx];
            packed0[gp] = make_uint2(key, sval[idx]);
            klab[gp] = (u16)(key >> 18);
        }
    } else if (bid < np1 + CVT_B) {
        // ---------------- convert role: f32 -> bf16, 2 float4 items per thread ----------------
        const int n4 = N_TOTAL * LATENT / 4;
        const int ub = NUM_USERS * LATENT / 4;
        const int T  = CVT_B * P1_T;
        int g = (bid - np1) * P1_T + t;
        #pragma unroll
        for (int rep = 0; rep < 2; ++rep) {
            int i = g + rep * T;
            if (i < n4) {
                float4 f = (i < ub) ? reinterpret_cast<const float4*>(ue)[i]
                                    : reinterpret_cast<const float4*>(ie)[i - ub];
                ushort4 o;
                o.x = f32_to_bf16(f.x); o.y = f32_to_bf16(f.y);
                o.z = f32_to_bf16(f.z); o.w = f32_to_bf16(f.w);
                reinterpret_cast<ushort4*>(emb0)[i] = o;
            }
        }
    } else {
        // ---------------- init_acc role: float4 per thread ----------------
        int g = (bid - np1 - CVT_B) * P1_T + t;     // 0 .. BATCH*16-1
        int b = g >> 4, dq = (g & 15) << 2;
        if (b < BATCH) {
            reinterpret_cast<float4*>(u_acc + (size_t)b * LATENT + dq)[0] =
                reinterpret_cast<const float4*>(ue + (size_t)users[b] * LATENT + dq)[0];
            reinterpret_cast<float4*>(i_acc + (size_t)b * LATENT + dq)[0] =
                reinterpret_cast<const float4*>(ie + (size_t)items[b] * LATENT + dq)[0];
        }
    }
}

// ---- pass 2: self-scanning per-bucket counting sort; emits rowptr + compact edges ----
__global__ void __launch_bounds__(BROWS)
partition2_kernel(const int* __restrict__ ccur, const uint2* __restrict__ packed0,
                  const u16* __restrict__ klab,
                  uint2* __restrict__ edges, int* __restrict__ rowptr, int nnz) {
    __shared__ int cnt[BROWS];
    __shared__ int cur[BROWS];
    __shared__ int wsum[8];
    __shared__ int sOutb;
    int b = blockIdx.x;
    int t = threadIdx.x;

    // self-scan of the 293 bucket counts -> this bucket's output base
    int cv = (t < NB) ? ccur[t] : 0;
    int cexcl = block_excl_scan_512(cv, t, wsum);
    if (t == b) sOutb = cexcl;
    cnt[t] = 0;
    __syncthreads();
    int outb = sOutb;
    int count = ccur[b];

    const uint2* src = packed0 + (size_t)b * CAP;
    const u16*   kl  = klab + (size_t)b * CAP;
    // histogram from the compact 2B key stream
    for (int i = t; i < count; i += 2 * BROWS) {
        u16 k0 = kl[i];
        int i2 = i + BROWS;
        if (i2 < count) {
            u16 k1 = kl[i2];
            atomicAdd(&cnt[k0], 1);
            atomicAdd(&cnt[k1], 1);
        } else {
            atomicAdd(&cnt[k0], 1);
        }
    }
    __syncthreads();
    int v = cnt[t];
    int excl = block_excl_scan_512(v, t, wsum);
    cur[t] = excl;
    int r = (b << 9) + t;
    if (r < N_TOTAL) rowptr[r] = outb + excl;
    if (b == NB - 1 && t == 0) rowptr[N_TOTAL] = nnz;
    __syncthreads();
    for (int i = t; i < count; i += 2 * BROWS) {
        uint2 p0 = src[i];
        int i2 = i + BROWS;
        if (i2 < count) {
            uint2 p1 = src[i2];
            int pos0 = outb + atomicAdd(&cur[p0.x >> 18], 1);
            int pos1 = outb + atomicAdd(&cur[p1.x >> 18], 1);
            edges[pos0] = make_uint2(p0.x & 0x3FFFFu, p0.y);
            edges[pos1] = make_uint2(p1.x & 0x3FFFFu, p1.y);
        } else {
            int pos0 = outb + atomicAdd(&cur[p0.x >> 18], 1);
            edges[pos0] = make_uint2(p0.x & 0x3FFFFu, p0.y);
        }
    }
}

// ---- row tail: 8-edge then guarded 4-edge loops (no reduce) ----
__device__ __forceinline__ void row_tail(const uint2* __restrict__ edges,
                                         const u16* __restrict__ x,
                                         int i, int e, int j, int q, float acc[4]) {
    for (; i + 8 <= e; i += 8) {
        uint2 e0 = edges[i + j];
        uint2 e1 = edges[i + 4 + j];
        uint2 x0 = *reinterpret_cast<const uint2*>(x + (size_t)e0.x * LATENT + q);
        uint2 x1 = *reinterpret_cast<const uint2*>(x + (size_t)e1.x * LATENT + q);
        fma4(acc, x0, __uint_as_float(e0.y));
        fma4(acc, x1, __uint_as_float(e1.y));
    }
    for (; i < e; i += 4) {
        // memory-safe: edges has >=16 zero-padded entries past nnz; reading the
        // next row's edge is fine because v is forced to 0 for out-of-row slots
        uint2 e0 = edges[i + j];
        float v0 = (i + j < e) ? __uint_as_float(e0.y) : 0.f;
        uint2 x0 = *reinterpret_cast<const uint2*>(x + (size_t)e0.x * LATENT + q);
        fma4(acc, x0, v0);
    }
}

// ---- single-row SpMM core (used by batch kernel) ----
__device__ __forceinline__ void spmm_row(const uint2* __restrict__ edges,
                                         const u16* __restrict__ x,
                                         int s, int e, int lane, float acc[4]) {
    int j = lane >> 4;
    int q = (lane & 15) << 2;
    acc[0] = acc[1] = acc[2] = acc[3] = 0.f;
    int i = s;
    for (; i + 16 <= e; i += 16) {
        uint2 e0 = edges[i + j];
        uint2 e1 = edges[i + 4 + j];
        uint2 e2 = edges[i + 8 + j];
        uint2 e3 = edges[i + 12 + j];
        uint2 x0 = *reinterpret_cast<const uint2*>(x + (size_t)e0.x * LATENT + q);
        uint2 x1 = *reinterpret_cast<const uint2*>(x + (size_t)e1.x * LATENT + q);
        uint2 x2 = *reinterpret_cast<const uint2*>(x + (size_t)e2.x * LATENT + q);
        uint2 x3 = *reinterpret_cast<const uint2*>(x + (size_t)e3.x * LATENT + q);
        fma4(acc, x0, __uint_as_float(e0.y));
        fma4(acc, x1, __uint_as_float(e1.y));
        fma4(acc, x2, __uint_as_float(e2.y));
        fma4(acc, x3, __uint_as_float(e3.y));
    }
    row_tail(edges, x, i, e, j, q, acc);
    #pragma unroll
    for (int k = 0; k < 4; ++k) {
        acc[k] += __shfl_xor(acc[k], 16, 64);
        acc[k] += __shfl_xor(acc[k], 32, 64);
    }
}

// ---- two-row SpMM body (writes bf16 rows r0, r0+1) ----
__device__ __forceinline__ void spmm_two_rows(const int* __restrict__ rowptr,
                                              const uint2* __restrict__ edges,
                                              const u16* __restrict__ x,
                                              u16* __restrict__ y,
                                              int wid, int lane) {
    int r0 = wid * 2;
    int j = lane >> 4;
    int q = (lane & 15) << 2;
    int i0 = rowptr[r0];
    int e0 = rowptr[r0 + 1];
    int i1 = e0;
    int e1 = rowptr[r0 + 2];
    float a0[4] = {0.f, 0.f, 0.f, 0.f};
    float a1[4] = {0.f, 0.f, 0.f, 0.f};

    while (i0 + 8 <= e0 && i1 + 8 <= e1) {
        uint2 p00 = edges[i0 + j];
        uint2 p01 = edges[i0 + 4 + j];
        uint2 p10 = edges[i1 + j];
        uint2 p11 = edges[i1 + 4 + j];
        uint2 g00 = *reinterpret_cast<const uint2*>(x + (size_t)p00.x * LATENT + q);
        uint2 g01 = *reinterpret_cast<const uint2*>(x + (size_t)p01.x * LATENT + q);
        uint2 g10 = *reinterpret_cast<const uint2*>(x + (size_t)p10.x * LATENT + q);
        uint2 g11 = *reinterpret_cast<const uint2*>(x + (size_t)p11.x * LATENT + q);
        fma4(a0, g00, __uint_as_float(p00.y));
        fma4(a0, g01, __uint_as_float(p01.y));
        fma4(a1, g10, __uint_as_float(p10.y));
        fma4(a1, g11, __uint_as_float(p11.y));
        i0 += 8;
        i1 += 8;
    }
    row_tail(edges, x, i0, e0, j, q, a0);
    row_tail(edges, x, i1, e1, j, q, a1);

    #pragma unroll
    for (int k = 0; k < 4; ++k) {
        a0[k] += __shfl_xor(a0[k], 16, 64);
        a0[k] += __shfl_xor(a0[k], 32, 64);
        a1[k] += __shfl_xor(a1[k], 16, 64);
        a1[k] += __shfl_xor(a1[k], 32, 64);
    }
    if (lane < 16) {
        u32 w0 = (u32)f32_to_bf16(a0[0]) | ((u32)f32_to_bf16(a0[1]) << 16);
        u32 w1 = (u32)f32_to_bf16(a0[2]) | ((u32)f32_to_bf16(a0[3]) << 16);
        *reinterpret_cast<uint2*>(y + (size_t)r0 * LATENT + (lane << 2)) = make_uint2(w0, w1);
        u32 w2 = (u32)f32_to_bf16(a1[0]) | ((u32)f32_to_bf16(a1[1]) << 16);
        u32 w3 = (u32)f32_to_bf16(a1[2]) | ((u32)f32_to_bf16(a1[3]) << 16);
        *reinterpret_cast<uint2*>(y + (size_t)(r0 + 1) * LATENT + (lane << 2)) = make_uint2(w2, w3);
    }
}

// ---- gather-acc role body: uint2 (4 bf16 dims) per thread ----
__device__ __forceinline__ void gather_role(const u16* __restrict__ emb,
                                            const int* __restrict__ users,
                                            const int* __restrict__ items,
                                            float* __restrict__ u_acc,
                                            float* __restrict__ i_acc, int g) {
    int b = g >> 4, dq = (g & 15) << 2;
    if (b >= BATCH) return;
    uint2 xu = *reinterpret_cast<const uint2*>(emb + (size_t)users[b] * LATENT + dq);
    uint2 xi = *reinterpret_cast<const uint2*>(emb + ((size_t)items[b] + NUM_USERS) * LATENT + dq);
    float4* pu = reinterpret_cast<float4*>(u_acc + (size_t)b * LATENT + dq);
    float4* pi = reinterpret_cast<float4*>(i_acc + (size_t)b * LATENT + dq);
    float4 ou = *pu, oi = *pi;
    ou.x += bf16_lo(xu.x); ou.y += bf16_hi(xu.x); ou.z += bf16_lo(xu.y); ou.w += bf16_hi(xu.y);
    oi.x += bf16_lo(xi.x); oi.y += bf16_hi(xi.x); oi.z += bf16_lo(xi.y); oi.w += bf16_hi(xi.y);
    *pu = ou; *pi = oi;
}

// ---- spmm layer 1 (pure) ----
__global__ void spmm_kernel(const int* __restrict__ rowptr, const uint2* __restrict__ edges,
                            const u16* __restrict__ x, u16* __restrict__ y) {
    int wid = blockIdx.x * 4 + (threadIdx.x >> 6);
    spmm_two_rows(rowptr, edges, x, y, wid, threadIdx.x & 63);
}

// ---- spmm layer 2 + gather_acc(layer-1 output) fat kernel (disjoint buffers: safe) ----
__global__ void spmm_gather_kernel(const int* __restrict__ rowptr, const uint2* __restrict__ edges,
                                   const u16* __restrict__ x, u16* __restrict__ y,
                                   const int* __restrict__ users, const int* __restrict__ items,
                                   float* __restrict__ u_acc, float* __restrict__ i_acc,
                                   int nspmm) {
    int bid = blockIdx.x;
    if (bid < nspmm) {
        int wid = bid * 4 + (threadIdx.x >> 6);
        spmm_two_rows(rowptr, edges, x, y, wid, threadIdx.x & 63);
    } else {
        gather_role(x, users, items, u_acc, i_acc, (bid - nspmm) * 256 + threadIdx.x);
    }
}

// ---- layer 3: batch-rows-only SpMM with layer-2 gather FOLDED into the epilogue ----
// (single RMW per u_acc/i_acc address in this kernel -> no race)
__global__ void spmm_batch_kernel(const int* __restrict__ rowptr, const uint2* __restrict__ edges,
                                  const u16* __restrict__ x,
                                  const int* __restrict__ users, const int* __restrict__ items,
                                  float* __restrict__ u_acc, float* __restrict__ i_acc) {
    int slot = blockIdx.x * 4 + (threadIdx.x >> 6);   // 0 .. 2*BATCH-1
    int lane = threadIdx.x & 63;
    int row = (slot < BATCH) ? users[slot] : (NUM_USERS + items[slot - BATCH]);
    int s = rowptr[row], e = rowptr[row + 1];
    float acc[4];
    spmm_row(edges, x, s, e, lane, acc);
    if (lane < 16) {
        // layer-2 contribution: this row's own embedding (input x of this kernel)
        uint2 xr = *reinterpret_cast<const uint2*>(x + (size_t)row * LATENT + (lane << 2));
        float* dst = (slot < BATCH) ? (u_acc + (size_t)slot * LATENT)
                                    : (i_acc + (size_t)(slot - BATCH) * LATENT);
        float4* p = reinterpret_cast<float4*>(dst + (lane << 2));
        float4 old = *p;
        old.x += acc[0] + bf16_lo(xr.x);
        old.y += acc[1] + bf16_hi(xr.x);
        old.z += acc[2] + bf16_lo(xr.y);
        old.w += acc[3] + bf16_hi(xr.y);
        *p = old;
    }
}

// ---- gamma[b] = dot(u_acc[b], i_acc[b]) / 16 ; 8 rows per 512-thread block ----
__global__ void dot_kernel(const float* __restrict__ u_acc,
                           const float* __restrict__ i_acc,
                           float* __restrict__ out) {
    int b = blockIdx.x * 8 + (threadIdx.x >> 6);
    int d = threadIdx.x & 63;
    float p = u_acc[b * 64 + d] * i_acc[b * 64 + d];
    #pragma unroll
    for (int off = 32; off; off >>= 1) p += __shfl_down(p, off, 64);
    if (d == 0) out[b] = p * (1.0f / 16.0f);
}

extern "C" void kernel_launch(void* const* d_in, const int* in_sizes, int n_in,
                              void* d_out, int out_size, void* d_ws, size_t ws_size,
                              hipStream_t stream) {
    const float* user_emb = (const float*)d_in[0];
    const float* item_emb = (const float*)d_in[1];
    const float* vals     = (const float*)d_in[2];
    const int*   rows     = (const int*)d_in[3];
    const int*   cols     = (const int*)d_in[4];
    const int*   users    = (const int*)d_in[5];
    const int*   items    = (const int*)d_in[6];
    float* out = (float*)d_out;

    const int nnz = in_sizes[2];
    const int np1 = (nnz + P1_C - 1) / P1_C;

    char* ws = (char*)d_ws;
    const size_t embB   = (size_t)N_TOTAL * LATENT * sizeof(u16);     // 19.2 MB
    const size_t accB   = (size_t)BATCH * LATENT * sizeof(float);     // 4 MB
    const size_t slabB  = (size_t)NB * CAP * sizeof(uint2);           // 38.4 MB
    const size_t klabB  = (size_t)NB * CAP * sizeof(u16);             // 9.6 MB
    const size_t edgeB  = (size_t)(nnz + 16) * sizeof(uint2);         // 32 MB + pad

    size_t off = 0;
    u16*   emb_a   = (u16*)  (ws + off); off += embB;
    u16*   emb_b   = (u16*)  (ws + off); off += embB;
    uint2* packed0 = (uint2*)(ws + off); off += slabB;
    u16*   klab    = (u16*)  (ws + off); off += klabB;
    uint2* edges   = (uint2*)(ws + off); off += edgeB;
    float* u_acc   = (float*)(ws + off); off += accB;
    float* i_acc   = (float*)(ws + off); off += accB;
    int*   rowptr  = (int*)  (ws + off); off += (size_t)(N_TOTAL + 1) * sizeof(int);
    int*   ccur    = (int*)  (ws + off); off += (size_t)(NB + 1) * sizeof(int);

    hipMemsetAsync(ccur, 0, (size_t)(NB + 1) * sizeof(int), stream);
    hipMemsetAsync(edges + nnz, 0, 16 * sizeof(uint2), stream);   // tail padding

    // A: partition1 + convert + init_acc (independent roles, one launch)
    fatA_kernel<<<np1 + CVT_B + INIT_B, P1_T, 0, stream>>>(
        rows, cols, vals, ccur, packed0, klab,
        user_emb, item_emb, emb_a, users, items, u_acc, i_acc, nnz, np1);

    // B: per-bucket counting sort (self-scans bucket counts)
    partition2_kernel<<<NB, BROWS, 0, stream>>>(ccur, packed0, klab, edges, rowptr, nnz);

    // layer 1
    spmm_kernel<<<N_TOTAL / 8, 256, 0, stream>>>(rowptr, edges, emb_a, emb_b);
    // layer 2 + gather_acc(layer 1)
    spmm_gather_kernel<<<N_TOTAL / 8 + GATH_B, 256, 0, stream>>>(
        rowptr, edges, emb_b, emb_a, users, items, u_acc, i_acc, N_TOTAL / 8);
    // layer 3 (batch rows only) with layer-2 gather folded into the epilogue
    spmm_batch_kernel<<<(2 * BATCH) / 4, 256, 0, stream>>>(
        rowptr, edges, emb_a, users, items, u_acc, i_acc);

    dot_kernel<<<BATCH / 8, 512, 0, stream>>>(u_acc, i_acc, out);
}